// Round 4
// baseline (11197.845 us; speedup 1.0000x reference)
//
#include <hip/hip_runtime.h>
#include <hip/hip_bf16.h>

// ---------------- problem constants ----------------
#define NN 30000
#define NE 480000
#define CIN 64
#define KD 1600          // 25*64 spline-K dimension
#define KT 1664          // + 64 root-append columns
#define KTILES 52        // 1664 / 32
#define KPA 1672         // padded A-tile row stride (elements)
#define NT 8             // nodes per fused block (= 8 waves, wave-per-node)
#define NB_FUSED (NN/NT) // 3750
#define REG_OFF  (30000*101)
#define OBJ_OFF  (30000*105)

typedef short bf16x8 __attribute__((ext_vector_type(8)));
typedef float f32x4  __attribute__((ext_vector_type(4)));

__device__ __forceinline__ ushort f2bf(float x) {
    union { float f; unsigned u; } v; v.f = x;
    unsigned r = v.u + 0x7FFFu + ((v.u >> 16) & 1u);   // RNE
    return (ushort)(r >> 16);
}

// ---------------- graph preprocessing ----------------
__global__ void k_count(const int* __restrict__ dst, int* __restrict__ deg) {
    int e = blockIdx.x * 256 + threadIdx.x;
    if (e < NE) atomicAdd(&deg[dst[e]], 1);
}

__global__ void k_scan(const int* __restrict__ deg, int* __restrict__ rp,
                       int* __restrict__ cur, float* __restrict__ invd) {
    __shared__ int s[1024];
    int t = threadIdx.x;
    const int CH = 30;                       // 1024*30 >= 30000
    int base = t * CH, loc = 0;
    for (int i = 0; i < CH; ++i) { int n = base + i; if (n < NN) loc += deg[n]; }
    s[t] = loc; __syncthreads();
    for (int o = 1; o < 1024; o <<= 1) {
        int v = (t >= o) ? s[t - o] : 0;
        __syncthreads(); s[t] += v; __syncthreads();
    }
    int run = s[t] - loc;                    // exclusive prefix for this chunk
    for (int i = 0; i < CH; ++i) {
        int n = base + i;
        if (n < NN) {
            int dg = deg[n];
            rp[n] = run; cur[n] = run;
            invd[n] = 1.f / (float)(dg > 0 ? dg : 1);
            run += dg;
        }
    }
    if (t == 0) rp[NN] = NE;
}

// compute spline basis per edge and scatter metadata into dst-sorted order.
// pseudo in [0,1) -> i0,i1 in 0..3 -> NO clipping: corners are k00+{0,1,5,6}.
__global__ void k_scatter(const float* __restrict__ ea, const int* __restrict__ src,
                          const int* __restrict__ dst, int* __restrict__ cur,
                          float4* __restrict__ mB, int2* __restrict__ mI) {
    int e = blockIdx.x * 256 + threadIdx.x;
    if (e >= NE) return;
    float p0 = ea[e*3+0], p1 = ea[e*3+1];
    float v0 = p0*4.f, v1 = p1*4.f;
    float b0 = fminf(fmaxf(floorf(v0),0.f),4.f);
    float b1 = fminf(fmaxf(floorf(v1),0.f),4.f);
    float f0 = v0-b0, f1 = v1-b1;
    int i0 = (int)b0, i1 = (int)b1;
    // corner order matches bits [[0,0],[0,1],[1,0],[1,1]]:
    float B00 = (1.f-f0)*(1.f-f1);   // k00
    float B01 = (1.f-f0)*f1;         // k00+1
    float B10 = f0*(1.f-f1);         // k00+5
    float B11 = f0*f1;               // k00+6
    int k00 = i0*5 + i1;             // in {0..3,5..8,10..13,15..18}
    int dn = dst[e];
    int pos = atomicAdd(&cur[dn], 1);
    mB[pos] = make_float4(B00,B01,B10,B11);
    mI[pos] = make_int2(k00, src[e]);
}

// transpose+bf16 all 6 weight sets: Wt[d][kc] = W[kc][d] (kc<1600), = root[kc-1600][d]
__global__ void k_prepw(const float* W1,const float* R1,const float* W2,const float* R2,
                        const float* W3,const float* R3,const float* Wr,const float* Rr,
                        const float* Wc,const float* Rc,const float* Wo,const float* Ro,
                        ushort* T1, ushort* T2, ushort* T3, ushort* Tr, ushort* Tc, ushort* To) {
    int b = blockIdx.x;
    const float* W; const float* R; ushort* T; int od; int d;
    if      (b < 64)  { W=W1; R=R1; T=T1; od=64;  d=b;     }
    else if (b < 128) { W=W2; R=R2; T=T2; od=64;  d=b-64;  }
    else if (b < 192) { W=W3; R=R3; T=T3; od=64;  d=b-128; }
    else if (b < 208) { W=Wr; R=Rr; T=Tr; od=4;   d=b-192; }
    else if (b < 320) { W=Wc; R=Rc; T=Tc; od=101; d=b-208; }
    else              { W=Wo; R=Ro; T=To; od=1;   d=b-320; }
    for (int kc = threadIdx.x; kc < KT; kc += 256) {
        float v = 0.f;
        if (d < od) v = (kc < KD) ? W[(long)kc*od + d] : R[(long)(kc-KD)*od + d];
        T[(long)d*KT + kc] = f2bf(v);
    }
}

// ---------------- fused spline-conv building blocks ----------------
// Register-file aggregation: wave w owns node n0+w; lane l owns channel l.
// acc[25] lives in VGPRs; k00 is wave-uniform -> scalar switch, static reg idx.
#define AGG_CASE(K) case K: acc[K]+=bb.x*xu; acc[K+1]+=bb.y*xu; \
                            acc[K+5]+=bb.z*xu; acc[K+6]+=bb.w*xu; break;

__device__ __forceinline__ void build_tile(int n0, const int* __restrict__ rp,
        const float4* __restrict__ mB, const int2* __restrict__ mI,
        const float* __restrict__ f, const float* __restrict__ invd,
        ushort* accbh) {
    const int tid = threadIdx.x;
    const int w = tid >> 6, l = tid & 63;

    float acc[25];
    #pragma unroll
    for (int k = 0; k < 25; ++k) acc[k] = 0.f;

    int beg = rp[n0 + w], end = rp[n0 + w + 1];
    for (int e0 = beg; e0 < end; e0 += 4) {
        float4 b[4]; int2 m[4]; float xv[4];
        #pragma unroll
        for (int u = 0; u < 4; ++u) {
            int e = e0 + u;
            bool valid = e < end;
            int ee = valid ? e : beg;
            b[u] = mB[ee]; m[u] = mI[ee];
            xv[u] = f[(long)m[u].y * CIN + l];
            if (!valid) b[u] = make_float4(0,0,0,0);
        }
        #pragma unroll
        for (int u = 0; u < 4; ++u) {
            int k00 = __builtin_amdgcn_readfirstlane(m[u].x);
            float4 bb = b[u]; float xu = xv[u];
            switch (k00) {
                AGG_CASE(0)  AGG_CASE(1)  AGG_CASE(2)  AGG_CASE(3)
                AGG_CASE(5)  AGG_CASE(6)  AGG_CASE(7)  AGG_CASE(8)
                AGG_CASE(10) AGG_CASE(11) AGG_CASE(12) AGG_CASE(13)
                AGG_CASE(15) AGG_CASE(16) AGG_CASE(17) AGG_CASE(18)
                default: break;
            }
        }
    }

    // bf16 A-tile write: acc*invd for spline-K, raw x for root-append
    float s = invd[n0 + w];
    #pragma unroll
    for (int k = 0; k < 25; ++k)
        accbh[w*KPA + k*CIN + l] = f2bf(acc[k] * s);
    accbh[w*KPA + KD + l] = f2bf(f[(long)(n0 + w)*CIN + l]);
    __syncthreads();
}

// 16-col N-tile GEMM over kt in [k0, k0+NK): rows 0-7 valid (8-15 duplicate)
template<int NK>
__device__ __forceinline__ f32x4 sweepN(const ushort* accbh, const ushort* __restrict__ wt, int k0) {
    const int l = threadIdx.x & 63;
    const ushort* ap = accbh + (l & 7)*KPA + ((l >> 4) << 3) + k0*32;
    const ushort* bp = wt + (long)(l & 15)*KT + ((l >> 4) << 3) + k0*32;
    f32x4 d = {0.f,0.f,0.f,0.f};
    #pragma unroll
    for (int kt = 0; kt < NK; ++kt) {
        bf16x8 a = *(const bf16x8*)(ap + kt*32);
        bf16x8 b = *(const bf16x8*)(bp + kt*32);
        d = __builtin_amdgcn_mfma_f32_16x16x32_bf16(a, b, d, 0, 0, 0);
    }
    return d;
}

template<bool STATS, bool BIAS>
__device__ __forceinline__ void epilogue(f32x4 d, int n0, int colbase, int od, int ostride,
        const float* __restrict__ bias, float* __restrict__ out, float* __restrict__ stats) {
    const int l = threadIdx.x & 63;
    if (l >= 32) return;                      // lanes 32-63 hold duplicate rows
    int col = colbase + (l & 15);
    int rb = (l >> 4) << 2;                   // 0 or 4
    float bv = (BIAS && col < od) ? bias[col] : 0.f;
    float s1 = 0.f, s2 = 0.f;
    #pragma unroll
    for (int r = 0; r < 4; ++r) {
        float v = d[r] + bv;
        if (col < od) out[(long)(n0 + rb + r)*ostride + col] = v;
        s1 += v; s2 += v * v;
    }
    if (STATS) {
        s1 += __shfl_down(s1, 16);
        s2 += __shfl_down(s2, 16);
        if (l < 16) { atomicAdd(&stats[col], s1); atomicAdd(&stats[64 + col], s2); }
    }
}

// ---------------- fused conv kernels (512 threads, 3 blocks/CU) ----------------
__global__ __launch_bounds__(512,6) void k_conv1(const int* rp, const float4* mB, const int2* mI,
        const float* x, const float* invd, const ushort* T1, float* y1, float* st1) {
    __shared__ ushort accbh[NT*KPA];
    __shared__ f32x4 part[256];
    int n0 = blockIdx.x * NT;
    build_tile(n0, rp, mB, mI, x, invd, accbh);
    int tid = threadIdx.x, w = tid >> 6, l = tid & 63;
    int ct = w & 3, h = w >> 2;               // col-tile, K-half
    f32x4 d = sweepN<26>(accbh, T1 + (long)(ct << 4)*KT, h*26);
    if (h == 1) part[(ct << 6) + l] = d;
    __syncthreads();
    if (h == 0) {
        f32x4 o = d + part[(ct << 6) + l];
        epilogue<true,false>(o, n0, ct << 4, 64, 64, nullptr, y1, st1);
    }
}

__global__ __launch_bounds__(512,6) void k_conv23(const int* rp, const float4* mB, const int2* mI,
        const float* x1, const float* invd, const ushort* T2, const ushort* T3,
        float* y2, float* y3, float* st2, float* st3) {
    __shared__ ushort accbh[NT*KPA];
    int n0 = blockIdx.x * NT;
    build_tile(n0, rp, mB, mI, x1, invd, accbh);
    int w = threadIdx.x >> 6;
    if (w < 4) {
        f32x4 d = sweepN<52>(accbh, T2 + (long)(w << 4)*KT, 0);
        epilogue<true,false>(d, n0, w << 4, 64, 64, nullptr, y2, st2);
    } else {
        f32x4 d = sweepN<52>(accbh, T3 + (long)((w - 4) << 4)*KT, 0);
        epilogue<true,false>(d, n0, (w - 4) << 4, 64, 64, nullptr, y3, st3);
    }
}

__global__ __launch_bounds__(512,6) void k_regr(const int* rp, const float4* mB, const int2* mI,
        const float* x2, const float* invd, const ushort* Tr, const float* bias, float* outr) {
    __shared__ ushort accbh[NT*KPA];
    __shared__ f32x4 part[512];
    int n0 = blockIdx.x * NT;
    build_tile(n0, rp, mB, mI, x2, invd, accbh);
    int tid = threadIdx.x, w = tid >> 6, l = tid & 63;
    int kb = (w*52) >> 3, ke = ((w+1)*52) >> 3;
    const ushort* ap = accbh + (l & 7)*KPA + ((l >> 4) << 3);
    const ushort* bp = Tr + (long)(l & 15)*KT + ((l >> 4) << 3);
    f32x4 d = {0.f,0.f,0.f,0.f};
    for (int kt = kb; kt < ke; ++kt) {
        bf16x8 a = *(const bf16x8*)(ap + kt*32);
        bf16x8 b = *(const bf16x8*)(bp + kt*32);
        d = __builtin_amdgcn_mfma_f32_16x16x32_bf16(a, b, d, 0, 0, 0);
    }
    part[tid] = d; __syncthreads();
    if (w == 0) {
        f32x4 o = part[l];
        #pragma unroll
        for (int i = 1; i < 8; ++i) o += part[l + (i << 6)];
        epilogue<false,true>(o, n0, 0, 4, 4, bias, outr, nullptr);
    }
}

__global__ __launch_bounds__(512,6) void k_clsobj(const int* rp, const float4* mB, const int2* mI,
        const float* x3, const float* invd, const ushort* Tc, const ushort* To,
        const float* bc, const float* bo, float* outc, float* outo) {
    __shared__ ushort accbh[NT*KPA];
    int n0 = blockIdx.x * NT;
    build_tile(n0, rp, mB, mI, x3, invd, accbh);
    int w = threadIdx.x >> 6;
    const ushort* wt = (w < 7) ? (Tc + (long)(w << 4)*KT) : To;
    f32x4 d = sweepN<52>(accbh, wt, 0);
    if (w < 7) epilogue<false,true>(d, n0, w << 4, 101, 101, bc, outc, nullptr);
    else       epilogue<false,true>(d, n0, 0, 1, 1, bo, outo, nullptr);
}

// ---------------- BN + ReLU ----------------
__global__ void k_bnrelu(const float* __restrict__ y, const float* __restrict__ st,
                         const float* __restrict__ g, const float* __restrict__ bb,
                         float* __restrict__ xo) {
    int idx = blockIdx.x * 256 + threadIdx.x;
    if (idx >= NN*CIN) return;
    int d = idx & 63;
    const float inv_n = 1.f / (float)NN;
    float m = st[d] * inv_n;
    float var = st[64 + d] * inv_n - m * m;
    float v = (y[idx] - m) * rsqrtf(var + 1e-5f) * g[d] + bb[d];
    xo[idx] = fmaxf(v, 0.f);
}

// ---------------- host launch ----------------
extern "C" void kernel_launch(void* const* d_in, const int* in_sizes, int n_in,
                              void* d_out, int out_size, void* d_ws, size_t ws_size,
                              hipStream_t stream) {
    const float* x    = (const float*)d_in[0];
    const float* ea   = (const float*)d_in[1];
    const int*   src  = (const int*)d_in[2];
    const int*   dst  = (const int*)d_in[3];
    const float* W1   = (const float*)d_in[4];
    const float* R1   = (const float*)d_in[5];
    const float* g1   = (const float*)d_in[6];
    const float* be1  = (const float*)d_in[7];
    const float* W2   = (const float*)d_in[8];
    const float* R2   = (const float*)d_in[9];
    const float* g2   = (const float*)d_in[10];
    const float* be2  = (const float*)d_in[11];
    const float* W3   = (const float*)d_in[12];
    const float* R3   = (const float*)d_in[13];
    const float* g3   = (const float*)d_in[14];
    const float* be3  = (const float*)d_in[15];
    const float* Wr   = (const float*)d_in[16];
    const float* Rr   = (const float*)d_in[17];
    const float* br   = (const float*)d_in[18];
    const float* Wc   = (const float*)d_in[19];
    const float* Rc   = (const float*)d_in[20];
    const float* bc   = (const float*)d_in[21];
    const float* Wo   = (const float*)d_in[22];
    const float* Ro   = (const float*)d_in[23];
    const float* bo   = (const float*)d_in[24];
    float* out = (float*)d_out;

    char* p = (char*)d_ws;
    auto alloc = [&](size_t bytes) { char* r = p; p += (bytes + 255) & ~(size_t)255; return r; };
    float4* mB   = (float4*)alloc((size_t)NE * 16);
    int2*   mI   = (int2*)  alloc((size_t)NE * 8);
    int*    deg  = (int*)   alloc((size_t)NN * 4);
    int*    rp   = (int*)   alloc((size_t)(NN + 1) * 4);
    int*    cur  = (int*)   alloc((size_t)NN * 4);
    float*  invd = (float*) alloc((size_t)NN * 4);
    ushort* T1   = (ushort*)alloc((size_t)64  * KT * 2);
    ushort* T2   = (ushort*)alloc((size_t)64  * KT * 2);
    ushort* T3   = (ushort*)alloc((size_t)64  * KT * 2);
    ushort* Tr   = (ushort*)alloc((size_t)16  * KT * 2);
    ushort* Tc   = (ushort*)alloc((size_t)112 * KT * 2);
    ushort* To   = (ushort*)alloc((size_t)16  * KT * 2);
    float*  y1   = (float*) alloc((size_t)NN * CIN * 4);
    float*  y2   = (float*) alloc((size_t)NN * CIN * 4);
    float*  y3   = (float*) alloc((size_t)NN * CIN * 4);
    float*  x1   = (float*) alloc((size_t)NN * CIN * 4);
    float*  x2   = (float*) alloc((size_t)NN * CIN * 4);
    float*  x3   = (float*) alloc((size_t)NN * CIN * 4);
    float*  stats= (float*) alloc(3 * 128 * 4);
    float* st1 = stats, *st2 = stats + 128, *st3 = stats + 256;

    hipMemsetAsync(deg, 0, (size_t)NN * 4, stream);
    hipMemsetAsync(stats, 0, 3 * 128 * 4, stream);

    k_count  <<<1875, 256, 0, stream>>>(dst, deg);
    k_scan   <<<1, 1024, 0, stream>>>(deg, rp, cur, invd);
    k_scatter<<<1875, 256, 0, stream>>>(ea, src, dst, cur, mB, mI);
    k_prepw  <<<336, 256, 0, stream>>>(W1,R1,W2,R2,W3,R3,Wr,Rr,Wc,Rc,Wo,Ro,T1,T2,T3,Tr,Tc,To);

    k_conv1  <<<NB_FUSED, 512, 0, stream>>>(rp, mB, mI, x, invd, T1, y1, st1);
    k_bnrelu <<<7500, 256, 0, stream>>>(y1, st1, g1, be1, x1);
    k_conv23 <<<NB_FUSED, 512, 0, stream>>>(rp, mB, mI, x1, invd, T2, T3, y2, y3, st2, st3);
    k_bnrelu <<<7500, 256, 0, stream>>>(y2, st2, g2, be2, x2);
    k_bnrelu <<<7500, 256, 0, stream>>>(y3, st3, g3, be3, x3);
    k_regr   <<<NB_FUSED, 512, 0, stream>>>(rp, mB, mI, x2, invd, Tr, br, out + REG_OFF);
    k_clsobj <<<NB_FUSED, 512, 0, stream>>>(rp, mB, mI, x3, invd, Tc, To, bc, bo, out, out + OBJ_OFF);
}

// Round 5
// 8982.013 us; speedup vs baseline: 1.2467x; 1.2467x over previous
//
#include <hip/hip_runtime.h>
#include <hip/hip_bf16.h>

// ---------------- problem constants ----------------
#define NN 30000
#define NE 480000
#define CIN 64
#define KD 1600          // 25*64 spline-K dimension
#define KT 1664          // + 64 root-append columns
#define KTILES 52        // 1664 / 32
#define KPA 1672         // padded A-tile row stride (elements)
#define NT 16            // nodes per fused block (8 waves x 2 nodes, sequential)
#define NB_FUSED (NN/NT) // 1875
#define REG_OFF  (30000*101)
#define OBJ_OFF  (30000*105)

typedef short bf16x8 __attribute__((ext_vector_type(8)));
typedef float f32x4  __attribute__((ext_vector_type(4)));

__device__ __forceinline__ ushort f2bf(float x) {
    union { float f; unsigned u; } v; v.f = x;
    unsigned r = v.u + 0x7FFFu + ((v.u >> 16) & 1u);   // RNE
    return (ushort)(r >> 16);
}

// ---------------- graph preprocessing ----------------
__global__ void k_count(const int* __restrict__ dst, int* __restrict__ deg) {
    int e = blockIdx.x * 256 + threadIdx.x;
    if (e < NE) atomicAdd(&deg[dst[e]], 1);
}

__global__ void k_scan(const int* __restrict__ deg, int* __restrict__ rp,
                       int* __restrict__ cur, float* __restrict__ invd) {
    __shared__ int s[1024];
    int t = threadIdx.x;
    const int CH = 30;                       // 1024*30 >= 30000
    int base = t * CH, loc = 0;
    for (int i = 0; i < CH; ++i) { int n = base + i; if (n < NN) loc += deg[n]; }
    s[t] = loc; __syncthreads();
    for (int o = 1; o < 1024; o <<= 1) {
        int v = (t >= o) ? s[t - o] : 0;
        __syncthreads(); s[t] += v; __syncthreads();
    }
    int run = s[t] - loc;                    // exclusive prefix for this chunk
    for (int i = 0; i < CH; ++i) {
        int n = base + i;
        if (n < NN) {
            int dg = deg[n];
            rp[n] = run; cur[n] = run;
            invd[n] = 1.f / (float)(dg > 0 ? dg : 1);
            run += dg;
        }
    }
    if (t == 0) rp[NN] = NE;
}

// compute spline basis per edge and scatter metadata into dst-sorted order.
// pseudo in [0,1) -> i0,i1 in 0..3 -> NO clipping: corners are k00+{0,1,5,6}.
__global__ void k_scatter(const float* __restrict__ ea, const int* __restrict__ src,
                          const int* __restrict__ dst, int* __restrict__ cur,
                          float4* __restrict__ mB, int2* __restrict__ mI) {
    int e = blockIdx.x * 256 + threadIdx.x;
    if (e >= NE) return;
    float p0 = ea[e*3+0], p1 = ea[e*3+1];
    float v0 = p0*4.f, v1 = p1*4.f;
    float b0 = fminf(fmaxf(floorf(v0),0.f),4.f);
    float b1 = fminf(fmaxf(floorf(v1),0.f),4.f);
    float f0 = v0-b0, f1 = v1-b1;
    int i0 = (int)b0, i1 = (int)b1;
    // corner order matches bits [[0,0],[0,1],[1,0],[1,1]]:
    float B00 = (1.f-f0)*(1.f-f1);   // k00
    float B01 = (1.f-f0)*f1;         // k00+1
    float B10 = f0*(1.f-f1);         // k00+5
    float B11 = f0*f1;               // k00+6
    int k00 = i0*5 + i1;             // in {0..3,5..8,10..13,15..18}
    int dn = dst[e];
    int pos = atomicAdd(&cur[dn], 1);
    mB[pos] = make_float4(B00,B01,B10,B11);
    mI[pos] = make_int2(k00, src[e]);
}

// transpose+bf16 all 6 weight sets: Wt[d][kc] = W[kc][d] (kc<1600), = root[kc-1600][d]
__global__ void k_prepw(const float* W1,const float* R1,const float* W2,const float* R2,
                        const float* W3,const float* R3,const float* Wr,const float* Rr,
                        const float* Wc,const float* Rc,const float* Wo,const float* Ro,
                        ushort* T1, ushort* T2, ushort* T3, ushort* Tr, ushort* Tc, ushort* To) {
    int b = blockIdx.x;
    const float* W; const float* R; ushort* T; int od; int d;
    if      (b < 64)  { W=W1; R=R1; T=T1; od=64;  d=b;     }
    else if (b < 128) { W=W2; R=R2; T=T2; od=64;  d=b-64;  }
    else if (b < 192) { W=W3; R=R3; T=T3; od=64;  d=b-128; }
    else if (b < 208) { W=Wr; R=Rr; T=Tr; od=4;   d=b-192; }
    else if (b < 320) { W=Wc; R=Rc; T=Tc; od=101; d=b-208; }
    else              { W=Wo; R=Ro; T=To; od=1;   d=b-320; }
    for (int kc = threadIdx.x; kc < KT; kc += 256) {
        float v = 0.f;
        if (d < od) v = (kc < KD) ? W[(long)kc*od + d] : R[(long)(kc-KD)*od + d];
        T[(long)d*KT + kc] = f2bf(v);
    }
}

// ---------------- fused spline-conv building blocks ----------------
// Register-file aggregation: wave w owns nodes n0+2w, n0+2w+1 (sequential, one
// acc[25] live at a time); lane l owns channel l. k00 is wave-uniform -> scalar
// switch with compile-time register indices. Optional fused BN+ReLU on gather.
#define AGG_CASE(K) case K: acc[K]+=bb.x*xu; acc[K+1]+=bb.y*xu; \
                            acc[K+5]+=bb.z*xu; acc[K+6]+=bb.w*xu; break;

// per-lane BN params: v_norm = max(v*a + c, 0)
__device__ __forceinline__ void bn_params(const float* __restrict__ st,
        const float* __restrict__ g, const float* __restrict__ be,
        float& a, float& c) {
    int l = threadIdx.x & 63;
    const float inv_n = 1.f / (float)NN;
    float m = st[l] * inv_n;
    float var = st[64 + l] * inv_n - m * m;
    float rs = rsqrtf(var + 1e-5f);
    a = g[l] * rs;
    c = be[l] - m * a;
}

template<bool NORM>
__device__ __forceinline__ void build_tile(int n0, const int* __restrict__ rp,
        const float4* __restrict__ mB, const int2* __restrict__ mI,
        const float* __restrict__ f, const float* __restrict__ invd,
        float na, float nc, ushort* accbh) {
    const int tid = threadIdx.x;
    const int w = tid >> 6, l = tid & 63;
    for (int rep = 0; rep < 2; ++rep) {
        int row = (w << 1) + rep;
        int node = n0 + row;
        float acc[25];
        #pragma unroll
        for (int k = 0; k < 25; ++k) acc[k] = 0.f;
        int beg = rp[node], end = rp[node + 1];
        for (int e0 = beg; e0 < end; e0 += 4) {
            float4 b[4]; int2 m[4]; float xv[4];
            #pragma unroll
            for (int u = 0; u < 4; ++u) {
                int e = e0 + u;
                bool valid = e < end;
                int ee = valid ? e : beg;
                b[u] = mB[ee]; m[u] = mI[ee];
                if (!valid) b[u] = make_float4(0,0,0,0);
            }
            #pragma unroll
            for (int u = 0; u < 4; ++u) {
                float v = f[(long)m[u].y * CIN + l];
                if (NORM) v = fmaxf(v * na + nc, 0.f);
                xv[u] = v;
            }
            #pragma unroll
            for (int u = 0; u < 4; ++u) {
                int k00 = __builtin_amdgcn_readfirstlane(m[u].x);
                float4 bb = b[u]; float xu = xv[u];
                switch (k00) {
                    AGG_CASE(0)  AGG_CASE(1)  AGG_CASE(2)  AGG_CASE(3)
                    AGG_CASE(5)  AGG_CASE(6)  AGG_CASE(7)  AGG_CASE(8)
                    AGG_CASE(10) AGG_CASE(11) AGG_CASE(12) AGG_CASE(13)
                    AGG_CASE(15) AGG_CASE(16) AGG_CASE(17) AGG_CASE(18)
                    default: break;
                }
            }
        }
        float s = invd[node];
        #pragma unroll
        for (int k = 0; k < 25; ++k)
            accbh[row*KPA + k*CIN + l] = f2bf(acc[k] * s);
        float rv = f[(long)node * CIN + l];
        if (NORM) rv = fmaxf(rv * na + nc, 0.f);
        accbh[row*KPA + KD + l] = f2bf(rv);
    }
    __syncthreads();
}

// 16-col N-tile GEMM over kt in [k0, k0+NK): 16 valid A rows
template<int NK>
__device__ __forceinline__ f32x4 sweepN(const ushort* accbh, const ushort* __restrict__ wt, int k0) {
    const int l = threadIdx.x & 63;
    const ushort* ap = accbh + (l & 15)*KPA + ((l >> 4) << 3) + k0*32;
    const ushort* bp = wt + (long)(l & 15)*KT + ((l >> 4) << 3) + k0*32;
    f32x4 d = {0.f,0.f,0.f,0.f};
    #pragma unroll
    for (int kt = 0; kt < NK; ++kt) {
        bf16x8 a = *(const bf16x8*)(ap + kt*32);
        bf16x8 b = *(const bf16x8*)(bp + kt*32);
        d = __builtin_amdgcn_mfma_f32_16x16x32_bf16(a, b, d, 0, 0, 0);
    }
    return d;
}

template<bool STATS, bool BIAS>
__device__ __forceinline__ void epilogue(f32x4 d, int n0, int colbase, int od, int ostride,
        const float* __restrict__ bias, float* __restrict__ out, float* __restrict__ stats) {
    const int l = threadIdx.x & 63;
    int col = colbase + (l & 15);
    int rb = (l >> 4) << 2;                   // 0,4,8,12
    float bv = (BIAS && col < od) ? bias[col] : 0.f;
    float s1 = 0.f, s2 = 0.f;
    #pragma unroll
    for (int r = 0; r < 4; ++r) {
        float v = d[r] + bv;
        if (col < od) out[(long)(n0 + rb + r)*ostride + col] = v;
        s1 += v; s2 += v * v;
    }
    if (STATS) {
        s1 += __shfl_down(s1, 32); s2 += __shfl_down(s2, 32);
        s1 += __shfl_down(s1, 16); s2 += __shfl_down(s2, 16);
        if (l < 16) { atomicAdd(&stats[col], s1); atomicAdd(&stats[64 + col], s2); }
    }
}

// ---------------- fused conv kernels (512 threads, 2 blocks/CU) ----------------
__global__ __launch_bounds__(512,4) void k_conv1(const int* rp, const float4* mB, const int2* mI,
        const float* x, const float* invd, const ushort* T1, float* y1, float* st1) {
    __shared__ ushort accbh[NT*KPA];
    __shared__ f32x4 part[256];
    int n0 = blockIdx.x * NT;
    build_tile<false>(n0, rp, mB, mI, x, invd, 0.f, 0.f, accbh);
    int tid = threadIdx.x, w = tid >> 6, l = tid & 63;
    int ct = w & 3, h = w >> 2;               // col-tile, K-half
    f32x4 d = sweepN<26>(accbh, T1 + (long)(ct << 4)*KT, h*26);
    if (h) part[(ct << 6) + l] = d;
    __syncthreads();
    if (!h) {
        f32x4 o = d + part[(ct << 6) + l];
        epilogue<true,false>(o, n0, ct << 4, 64, 64, nullptr, y1, st1);
    }
}

__global__ __launch_bounds__(512,4) void k_conv23(const int* rp, const float4* mB, const int2* mI,
        const float* y1, const float* invd,
        const float* st1, const float* g1, const float* be1,
        const ushort* T2, const ushort* T3,
        float* y2, float* y3, float* st2, float* st3) {
    __shared__ ushort accbh[NT*KPA];
    float a, c; bn_params(st1, g1, be1, a, c);
    int n0 = blockIdx.x * NT;
    build_tile<true>(n0, rp, mB, mI, y1, invd, a, c, accbh);
    int w = threadIdx.x >> 6;
    if (w < 4) {
        f32x4 d = sweepN<52>(accbh, T2 + (long)(w << 4)*KT, 0);
        epilogue<true,false>(d, n0, w << 4, 64, 64, nullptr, y2, st2);
    } else {
        f32x4 d = sweepN<52>(accbh, T3 + (long)((w - 4) << 4)*KT, 0);
        epilogue<true,false>(d, n0, (w - 4) << 4, 64, 64, nullptr, y3, st3);
    }
}

__global__ __launch_bounds__(512,4) void k_regr(const int* rp, const float4* mB, const int2* mI,
        const float* y2, const float* invd,
        const float* st2, const float* g2, const float* be2,
        const ushort* Tr, const float* bias, float* outr) {
    __shared__ ushort accbh[NT*KPA];
    __shared__ f32x4 part[512];
    float a, c; bn_params(st2, g2, be2, a, c);
    int n0 = blockIdx.x * NT;
    build_tile<true>(n0, rp, mB, mI, y2, invd, a, c, accbh);
    int tid = threadIdx.x, w = tid >> 6, l = tid & 63;
    int kb = (w*52) >> 3, ke = ((w+1)*52) >> 3;
    const ushort* ap = accbh + (l & 15)*KPA + ((l >> 4) << 3);
    const ushort* bp = Tr + (long)(l & 15)*KT + ((l >> 4) << 3);
    f32x4 d = {0.f,0.f,0.f,0.f};
    for (int kt = kb; kt < ke; ++kt) {
        bf16x8 av = *(const bf16x8*)(ap + kt*32);
        bf16x8 bv = *(const bf16x8*)(bp + kt*32);
        d = __builtin_amdgcn_mfma_f32_16x16x32_bf16(av, bv, d, 0, 0, 0);
    }
    part[tid] = d; __syncthreads();
    if (w == 0) {
        f32x4 o = part[l];
        #pragma unroll
        for (int i = 1; i < 8; ++i) o += part[l + (i << 6)];
        epilogue<false,true>(o, n0, 0, 4, 4, bias, outr, nullptr);
    }
}

__global__ __launch_bounds__(512,4) void k_clsobj(const int* rp, const float4* mB, const int2* mI,
        const float* y3, const float* invd,
        const float* st3, const float* g3, const float* be3,
        const ushort* Tc, const ushort* To,
        const float* bc, const float* bo, float* outc, float* outo) {
    __shared__ ushort accbh[NT*KPA];
    float a, c; bn_params(st3, g3, be3, a, c);
    int n0 = blockIdx.x * NT;
    build_tile<true>(n0, rp, mB, mI, y3, invd, a, c, accbh);
    int w = threadIdx.x >> 6;
    const ushort* wt = (w < 7) ? (Tc + (long)(w << 4)*KT) : To;
    f32x4 d = sweepN<52>(accbh, wt, 0);
    if (w < 7) epilogue<false,true>(d, n0, w << 4, 101, 101, bc, outc, nullptr);
    else       epilogue<false,true>(d, n0, 0, 1, 1, bo, outo, nullptr);
}

// ---------------- host launch ----------------
extern "C" void kernel_launch(void* const* d_in, const int* in_sizes, int n_in,
                              void* d_out, int out_size, void* d_ws, size_t ws_size,
                              hipStream_t stream) {
    const float* x    = (const float*)d_in[0];
    const float* ea   = (const float*)d_in[1];
    const int*   src  = (const int*)d_in[2];
    const int*   dst  = (const int*)d_in[3];
    const float* W1   = (const float*)d_in[4];
    const float* R1   = (const float*)d_in[5];
    const float* g1   = (const float*)d_in[6];
    const float* be1  = (const float*)d_in[7];
    const float* W2   = (const float*)d_in[8];
    const float* R2   = (const float*)d_in[9];
    const float* g2   = (const float*)d_in[10];
    const float* be2  = (const float*)d_in[11];
    const float* W3   = (const float*)d_in[12];
    const float* R3   = (const float*)d_in[13];
    const float* g3   = (const float*)d_in[14];
    const float* be3  = (const float*)d_in[15];
    const float* Wr   = (const float*)d_in[16];
    const float* Rr   = (const float*)d_in[17];
    const float* br   = (const float*)d_in[18];
    const float* Wc   = (const float*)d_in[19];
    const float* Rc   = (const float*)d_in[20];
    const float* bc   = (const float*)d_in[21];
    const float* Wo   = (const float*)d_in[22];
    const float* Ro   = (const float*)d_in[23];
    const float* bo   = (const float*)d_in[24];
    float* out = (float*)d_out;

    char* p = (char*)d_ws;
    auto alloc = [&](size_t bytes) { char* r = p; p += (bytes + 255) & ~(size_t)255; return r; };
    float4* mB   = (float4*)alloc((size_t)NE * 16);
    int2*   mI   = (int2*)  alloc((size_t)NE * 8);
    int*    deg  = (int*)   alloc((size_t)NN * 4);
    int*    rp   = (int*)   alloc((size_t)(NN + 1) * 4);
    int*    cur  = (int*)   alloc((size_t)NN * 4);
    float*  invd = (float*) alloc((size_t)NN * 4);
    ushort* T1   = (ushort*)alloc((size_t)64  * KT * 2);
    ushort* T2   = (ushort*)alloc((size_t)64  * KT * 2);
    ushort* T3   = (ushort*)alloc((size_t)64  * KT * 2);
    ushort* Tr   = (ushort*)alloc((size_t)16  * KT * 2);
    ushort* Tc   = (ushort*)alloc((size_t)112 * KT * 2);
    ushort* To   = (ushort*)alloc((size_t)16  * KT * 2);
    float*  y1   = (float*) alloc((size_t)NN * CIN * 4);
    float*  y2   = (float*) alloc((size_t)NN * CIN * 4);
    float*  y3   = (float*) alloc((size_t)NN * CIN * 4);
    float*  stats= (float*) alloc(3 * 128 * 4);
    float* st1 = stats, *st2 = stats + 128, *st3 = stats + 256;

    hipMemsetAsync(deg, 0, (size_t)NN * 4, stream);
    hipMemsetAsync(stats, 0, 3 * 128 * 4, stream);

    k_count  <<<1875, 256, 0, stream>>>(dst, deg);
    k_scan   <<<1, 1024, 0, stream>>>(deg, rp, cur, invd);
    k_scatter<<<1875, 256, 0, stream>>>(ea, src, dst, cur, mB, mI);
    k_prepw  <<<336, 256, 0, stream>>>(W1,R1,W2,R2,W3,R3,Wr,Rr,Wc,Rc,Wo,Ro,T1,T2,T3,Tr,Tc,To);

    k_conv1  <<<NB_FUSED, 512, 0, stream>>>(rp, mB, mI, x, invd, T1, y1, st1);
    k_conv23 <<<NB_FUSED, 512, 0, stream>>>(rp, mB, mI, y1, invd, st1, g1, be1, T2, T3, y2, y3, st2, st3);
    k_regr   <<<NB_FUSED, 512, 0, stream>>>(rp, mB, mI, y2, invd, st2, g2, be2, Tr, br, out + REG_OFF);
    k_clsobj <<<NB_FUSED, 512, 0, stream>>>(rp, mB, mI, y3, invd, st3, g3, be3, Tc, To, bc, bo, out, out + OBJ_OFF);
}

// Round 6
// 684.395 us; speedup vs baseline: 16.3617x; 13.1240x over previous
//
#include <hip/hip_runtime.h>
#include <hip/hip_bf16.h>

// ---------------- problem constants ----------------
#define NN 30000
#define NE 480000
#define CIN 64
#define KD 1600          // 25*64 spline-K dimension
#define KT 1664          // + 64 root-append columns
#define KTILES 52        // 1664 / 32
#define KPA 1672         // padded A-tile row stride (elements)
#define NT 16            // nodes per fused block (8 waves x 2 nodes, sequential)
#define NB_FUSED (NN/NT) // 1875
#define REG_OFF  (30000*101)
#define OBJ_OFF  (30000*105)

typedef short bf16x8 __attribute__((ext_vector_type(8)));
typedef float f32x4  __attribute__((ext_vector_type(4)));

__device__ __forceinline__ ushort f2bf(float x) {
    union { float f; unsigned u; } v; v.f = x;
    unsigned r = v.u + 0x7FFFu + ((v.u >> 16) & 1u);   // RNE
    return (ushort)(r >> 16);
}

// ---------------- graph preprocessing ----------------
__global__ void k_count(const int* __restrict__ dst, int* __restrict__ deg) {
    int e = blockIdx.x * 256 + threadIdx.x;
    if (e < NE) atomicAdd(&deg[dst[e]], 1);
}

__global__ void k_scan(const int* __restrict__ deg, int* __restrict__ rp,
                       int* __restrict__ cur, float* __restrict__ invd) {
    __shared__ int s[1024];
    int t = threadIdx.x;
    const int CH = 30;                       // 1024*30 >= 30000
    int base = t * CH, loc = 0;
    for (int i = 0; i < CH; ++i) { int n = base + i; if (n < NN) loc += deg[n]; }
    s[t] = loc; __syncthreads();
    for (int o = 1; o < 1024; o <<= 1) {
        int v = (t >= o) ? s[t - o] : 0;
        __syncthreads(); s[t] += v; __syncthreads();
    }
    int run = s[t] - loc;                    // exclusive prefix for this chunk
    for (int i = 0; i < CH; ++i) {
        int n = base + i;
        if (n < NN) {
            int dg = deg[n];
            rp[n] = run; cur[n] = run;
            invd[n] = 1.f / (float)(dg > 0 ? dg : 1);
            run += dg;
        }
    }
    if (t == 0) rp[NN] = NE;
}

// compute spline basis per edge and scatter metadata into dst-sorted order.
// pseudo in [0,1) -> i0,i1 in 0..3 -> NO clipping: corners are k00+{0,1,5,6}.
__global__ void k_scatter(const float* __restrict__ ea, const int* __restrict__ src,
                          const int* __restrict__ dst, int* __restrict__ cur,
                          float4* __restrict__ mB, int2* __restrict__ mI) {
    int e = blockIdx.x * 256 + threadIdx.x;
    if (e >= NE) return;
    float p0 = ea[e*3+0], p1 = ea[e*3+1];
    float v0 = p0*4.f, v1 = p1*4.f;
    float b0 = fminf(fmaxf(floorf(v0),0.f),4.f);
    float b1 = fminf(fmaxf(floorf(v1),0.f),4.f);
    float f0 = v0-b0, f1 = v1-b1;
    int i0 = (int)b0, i1 = (int)b1;
    // corner order matches bits [[0,0],[0,1],[1,0],[1,1]]:
    float B00 = (1.f-f0)*(1.f-f1);   // k00
    float B01 = (1.f-f0)*f1;         // k00+1
    float B10 = f0*(1.f-f1);         // k00+5
    float B11 = f0*f1;               // k00+6
    int k00 = i0*5 + i1;             // in {0..3,5..8,10..13,15..18}
    int dn = dst[e];
    int pos = atomicAdd(&cur[dn], 1);
    mB[pos] = make_float4(B00,B01,B10,B11);
    mI[pos] = make_int2(k00, src[e]);
}

// transpose+bf16 all 6 weight sets: Wt[d][kc] = W[kc][d] (kc<1600), = root[kc-1600][d]
__global__ void k_prepw(const float* W1,const float* R1,const float* W2,const float* R2,
                        const float* W3,const float* R3,const float* Wr,const float* Rr,
                        const float* Wc,const float* Rc,const float* Wo,const float* Ro,
                        ushort* T1, ushort* T2, ushort* T3, ushort* Tr, ushort* Tc, ushort* To) {
    int b = blockIdx.x;
    const float* W; const float* R; ushort* T; int od; int d;
    if      (b < 64)  { W=W1; R=R1; T=T1; od=64;  d=b;     }
    else if (b < 128) { W=W2; R=R2; T=T2; od=64;  d=b-64;  }
    else if (b < 192) { W=W3; R=R3; T=T3; od=64;  d=b-128; }
    else if (b < 208) { W=Wr; R=Rr; T=Tr; od=4;   d=b-192; }
    else if (b < 320) { W=Wc; R=Rc; T=Tc; od=101; d=b-208; }
    else              { W=Wo; R=Ro; T=To; od=1;   d=b-320; }
    for (int kc = threadIdx.x; kc < KT; kc += 256) {
        float v = 0.f;
        if (d < od) v = (kc < KD) ? W[(long)kc*od + d] : R[(long)(kc-KD)*od + d];
        T[(long)d*KT + kc] = f2bf(v);
    }
}

// ---------------- fused spline-conv building blocks ----------------
// Register aggregation with 25 NAMED scalars (SROA-proof, no array, no scratch).
// Wave w owns nodes n0+2w, n0+2w+1 (sequential); lane l owns channel l.
// k00 is wave-uniform -> scalar switch with static register targets.

// per-lane BN params: v_norm = max(v*a + c, 0)
__device__ __forceinline__ void bn_params(const float* __restrict__ st,
        const float* __restrict__ g, const float* __restrict__ be,
        float& a, float& c) {
    int l = threadIdx.x & 63;
    const float inv_n = 1.f / (float)NN;
    float m = st[l] * inv_n;
    float var = st[64 + l] * inv_n - m * m;
    float rs = rsqrtf(var + 1e-5f);
    a = g[l] * rs;
    c = be[l] - m * a;
}

#define AGGC(K, A, B, C, D) case K: A += bb.x*xu; B += bb.y*xu; C += bb.z*xu; D += bb.w*xu; break;

template<bool NORM>
__device__ __forceinline__ void build_tile(int n0, const int* __restrict__ rp,
        const float4* __restrict__ mB, const int2* __restrict__ mI,
        const float* __restrict__ f, const float* __restrict__ invd,
        float na, float nc, ushort* accbh) {
    const int tid = threadIdx.x;
    const int w = tid >> 6, l = tid & 63;
    for (int rep = 0; rep < 2; ++rep) {
        int row = (w << 1) + rep;
        int node = n0 + row;
        float a00=0.f,a01=0.f,a02=0.f,a03=0.f,a04=0.f;
        float a05=0.f,a06=0.f,a07=0.f,a08=0.f,a09=0.f;
        float a10=0.f,a11=0.f,a12=0.f,a13=0.f,a14=0.f;
        float a15=0.f,a16=0.f,a17=0.f,a18=0.f,a19=0.f;
        float a20=0.f,a21=0.f,a22=0.f,a23=0.f,a24=0.f;
        int beg = rp[node], end = rp[node + 1];
        for (int e0 = beg; e0 < end; e0 += 4) {
            float4 b[4]; int2 m[4]; float xv[4];
            #pragma unroll
            for (int u = 0; u < 4; ++u) {
                int e = e0 + u;
                bool valid = e < end;
                int ee = valid ? e : beg;
                b[u] = mB[ee]; m[u] = mI[ee];
                if (!valid) b[u] = make_float4(0,0,0,0);
            }
            #pragma unroll
            for (int u = 0; u < 4; ++u) {
                float v = f[(long)m[u].y * CIN + l];
                if (NORM) v = fmaxf(v * na + nc, 0.f);
                xv[u] = v;
            }
            #pragma unroll
            for (int u = 0; u < 4; ++u) {
                int k00 = __builtin_amdgcn_readfirstlane(m[u].x);
                float4 bb = b[u]; float xu = xv[u];
                switch (k00) {
                    AGGC(0,  a00,a01,a05,a06)
                    AGGC(1,  a01,a02,a06,a07)
                    AGGC(2,  a02,a03,a07,a08)
                    AGGC(3,  a03,a04,a08,a09)
                    AGGC(5,  a05,a06,a10,a11)
                    AGGC(6,  a06,a07,a11,a12)
                    AGGC(7,  a07,a08,a12,a13)
                    AGGC(8,  a08,a09,a13,a14)
                    AGGC(10, a10,a11,a15,a16)
                    AGGC(11, a11,a12,a16,a17)
                    AGGC(12, a12,a13,a17,a18)
                    AGGC(13, a13,a14,a18,a19)
                    AGGC(15, a15,a16,a20,a21)
                    AGGC(16, a16,a17,a21,a22)
                    AGGC(17, a17,a18,a22,a23)
                    AGGC(18, a18,a19,a23,a24)
                    default: break;
                }
            }
        }
        float s = invd[node];
        ushort* rb = accbh + row*KPA + l;
        #define STO(K, V) rb[K*CIN] = f2bf((V) * s);
        STO(0,a00)  STO(1,a01)  STO(2,a02)  STO(3,a03)  STO(4,a04)
        STO(5,a05)  STO(6,a06)  STO(7,a07)  STO(8,a08)  STO(9,a09)
        STO(10,a10) STO(11,a11) STO(12,a12) STO(13,a13) STO(14,a14)
        STO(15,a15) STO(16,a16) STO(17,a17) STO(18,a18) STO(19,a19)
        STO(20,a20) STO(21,a21) STO(22,a22) STO(23,a23) STO(24,a24)
        #undef STO
        float rv = f[(long)node * CIN + l];
        if (NORM) rv = fmaxf(rv * na + nc, 0.f);
        rb[KD] = f2bf(rv);
    }
    __syncthreads();
}

// 16-col N-tile GEMM over kt in [k0, k0+NK): 16 valid A rows
template<int NK>
__device__ __forceinline__ f32x4 sweepN(const ushort* accbh, const ushort* __restrict__ wt, int k0) {
    const int l = threadIdx.x & 63;
    const ushort* ap = accbh + (l & 15)*KPA + ((l >> 4) << 3) + k0*32;
    const ushort* bp = wt + (long)(l & 15)*KT + ((l >> 4) << 3) + k0*32;
    f32x4 d = {0.f,0.f,0.f,0.f};
    #pragma unroll
    for (int kt = 0; kt < NK; ++kt) {
        bf16x8 a = *(const bf16x8*)(ap + kt*32);
        bf16x8 b = *(const bf16x8*)(bp + kt*32);
        d = __builtin_amdgcn_mfma_f32_16x16x32_bf16(a, b, d, 0, 0, 0);
    }
    return d;
}

template<bool STATS, bool BIAS>
__device__ __forceinline__ void epilogue(f32x4 d, int n0, int colbase, int od, int ostride,
        const float* __restrict__ bias, float* __restrict__ out, float* __restrict__ stats) {
    const int l = threadIdx.x & 63;
    int col = colbase + (l & 15);
    int rb = (l >> 4) << 2;                   // 0,4,8,12
    float bv = (BIAS && col < od) ? bias[col] : 0.f;
    float s1 = 0.f, s2 = 0.f;
    #pragma unroll
    for (int r = 0; r < 4; ++r) {
        float v = d[r] + bv;
        if (col < od) out[(long)(n0 + rb + r)*ostride + col] = v;
        s1 += v; s2 += v * v;
    }
    if (STATS) {
        s1 += __shfl_down(s1, 32); s2 += __shfl_down(s2, 32);
        s1 += __shfl_down(s1, 16); s2 += __shfl_down(s2, 16);
        if (l < 16) { atomicAdd(&stats[col], s1); atomicAdd(&stats[64 + col], s2); }
    }
}

// -------- fused conv kernels (512 threads; 2nd launch-bounds arg = BLOCKS/CU on this toolchain -> 128 VGPR cap) --------
__global__ __launch_bounds__(512,2) void k_conv1(const int* rp, const float4* mB, const int2* mI,
        const float* x, const float* invd, const ushort* T1, float* y1, float* st1) {
    __shared__ ushort accbh[NT*KPA];
    __shared__ f32x4 part[256];
    int n0 = blockIdx.x * NT;
    build_tile<false>(n0, rp, mB, mI, x, invd, 0.f, 0.f, accbh);
    int tid = threadIdx.x, w = tid >> 6, l = tid & 63;
    int ct = w & 3, h = w >> 2;               // col-tile, K-half
    f32x4 d = sweepN<26>(accbh, T1 + (long)(ct << 4)*KT, h*26);
    if (h) part[(ct << 6) + l] = d;
    __syncthreads();
    if (!h) {
        f32x4 o = d + part[(ct << 6) + l];
        epilogue<true,false>(o, n0, ct << 4, 64, 64, nullptr, y1, st1);
    }
}

__global__ __launch_bounds__(512,2) void k_conv23(const int* rp, const float4* mB, const int2* mI,
        const float* y1, const float* invd,
        const float* st1, const float* g1, const float* be1,
        const ushort* T2, const ushort* T3,
        float* y2, float* y3, float* st2, float* st3) {
    __shared__ ushort accbh[NT*KPA];
    float a, c; bn_params(st1, g1, be1, a, c);
    int n0 = blockIdx.x * NT;
    build_tile<true>(n0, rp, mB, mI, y1, invd, a, c, accbh);
    int w = threadIdx.x >> 6;
    if (w < 4) {
        f32x4 d = sweepN<52>(accbh, T2 + (long)(w << 4)*KT, 0);
        epilogue<true,false>(d, n0, w << 4, 64, 64, nullptr, y2, st2);
    } else {
        f32x4 d = sweepN<52>(accbh, T3 + (long)((w - 4) << 4)*KT, 0);
        epilogue<true,false>(d, n0, (w - 4) << 4, 64, 64, nullptr, y3, st3);
    }
}

__global__ __launch_bounds__(512,2) void k_regr(const int* rp, const float4* mB, const int2* mI,
        const float* y2, const float* invd,
        const float* st2, const float* g2, const float* be2,
        const ushort* Tr, const float* bias, float* outr) {
    __shared__ ushort accbh[NT*KPA];
    __shared__ f32x4 part[512];
    float a, c; bn_params(st2, g2, be2, a, c);
    int n0 = blockIdx.x * NT;
    build_tile<true>(n0, rp, mB, mI, y2, invd, a, c, accbh);
    int tid = threadIdx.x, w = tid >> 6, l = tid & 63;
    int kb = (w*52) >> 3, ke = ((w+1)*52) >> 3;
    const ushort* ap = accbh + (l & 15)*KPA + ((l >> 4) << 3);
    const ushort* bp = Tr + (long)(l & 15)*KT + ((l >> 4) << 3);
    f32x4 d = {0.f,0.f,0.f,0.f};
    for (int kt = kb; kt < ke; ++kt) {
        bf16x8 av = *(const bf16x8*)(ap + kt*32);
        bf16x8 bv = *(const bf16x8*)(bp + kt*32);
        d = __builtin_amdgcn_mfma_f32_16x16x32_bf16(av, bv, d, 0, 0, 0);
    }
    part[tid] = d; __syncthreads();
    if (w == 0) {
        f32x4 o = part[l];
        #pragma unroll
        for (int i = 1; i < 8; ++i) o += part[l + (i << 6)];
        epilogue<false,true>(o, n0, 0, 4, 4, bias, outr, nullptr);
    }
}

__global__ __launch_bounds__(512,2) void k_clsobj(const int* rp, const float4* mB, const int2* mI,
        const float* y3, const float* invd,
        const float* st3, const float* g3, const float* be3,
        const ushort* Tc, const ushort* To,
        const float* bc, const float* bo, float* outc, float* outo) {
    __shared__ ushort accbh[NT*KPA];
    float a, c; bn_params(st3, g3, be3, a, c);
    int n0 = blockIdx.x * NT;
    build_tile<true>(n0, rp, mB, mI, y3, invd, a, c, accbh);
    int w = threadIdx.x >> 6;
    const ushort* wt = (w < 7) ? (Tc + (long)(w << 4)*KT) : To;
    f32x4 d = sweepN<52>(accbh, wt, 0);
    if (w < 7) epilogue<false,true>(d, n0, w << 4, 101, 101, bc, outc, nullptr);
    else       epilogue<false,true>(d, n0, 0, 1, 1, bo, outo, nullptr);
}

// ---------------- host launch ----------------
extern "C" void kernel_launch(void* const* d_in, const int* in_sizes, int n_in,
                              void* d_out, int out_size, void* d_ws, size_t ws_size,
                              hipStream_t stream) {
    const float* x    = (const float*)d_in[0];
    const float* ea   = (const float*)d_in[1];
    const int*   src  = (const int*)d_in[2];
    const int*   dst  = (const int*)d_in[3];
    const float* W1   = (const float*)d_in[4];
    const float* R1   = (const float*)d_in[5];
    const float* g1   = (const float*)d_in[6];
    const float* be1  = (const float*)d_in[7];
    const float* W2   = (const float*)d_in[8];
    const float* R2   = (const float*)d_in[9];
    const float* g2   = (const float*)d_in[10];
    const float* be2  = (const float*)d_in[11];
    const float* W3   = (const float*)d_in[12];
    const float* R3   = (const float*)d_in[13];
    const float* g3   = (const float*)d_in[14];
    const float* be3  = (const float*)d_in[15];
    const float* Wr   = (const float*)d_in[16];
    const float* Rr   = (const float*)d_in[17];
    const float* br   = (const float*)d_in[18];
    const float* Wc   = (const float*)d_in[19];
    const float* Rc   = (const float*)d_in[20];
    const float* bc   = (const float*)d_in[21];
    const float* Wo   = (const float*)d_in[22];
    const float* Ro   = (const float*)d_in[23];
    const float* bo   = (const float*)d_in[24];
    float* out = (float*)d_out;

    char* p = (char*)d_ws;
    auto alloc = [&](size_t bytes) { char* r = p; p += (bytes + 255) & ~(size_t)255; return r; };
    float4* mB   = (float4*)alloc((size_t)NE * 16);
    int2*   mI   = (int2*)  alloc((size_t)NE * 8);
    int*    deg  = (int*)   alloc((size_t)NN * 4);
    int*    rp   = (int*)   alloc((size_t)(NN + 1) * 4);
    int*    cur  = (int*)   alloc((size_t)NN * 4);
    float*  invd = (float*) alloc((size_t)NN * 4);
    ushort* T1   = (ushort*)alloc((size_t)64  * KT * 2);
    ushort* T2   = (ushort*)alloc((size_t)64  * KT * 2);
    ushort* T3   = (ushort*)alloc((size_t)64  * KT * 2);
    ushort* Tr   = (ushort*)alloc((size_t)16  * KT * 2);
    ushort* Tc   = (ushort*)alloc((size_t)112 * KT * 2);
    ushort* To   = (ushort*)alloc((size_t)16  * KT * 2);
    float*  y1   = (float*) alloc((size_t)NN * CIN * 4);
    float*  y2   = (float*) alloc((size_t)NN * CIN * 4);
    float*  y3   = (float*) alloc((size_t)NN * CIN * 4);
    float*  stats= (float*) alloc(3 * 128 * 4);
    float* st1 = stats, *st2 = stats + 128, *st3 = stats + 256;

    hipMemsetAsync(deg, 0, (size_t)NN * 4, stream);
    hipMemsetAsync(stats, 0, 3 * 128 * 4, stream);

    k_count  <<<1875, 256, 0, stream>>>(dst, deg);
    k_scan   <<<1, 1024, 0, stream>>>(deg, rp, cur, invd);
    k_scatter<<<1875, 256, 0, stream>>>(ea, src, dst, cur, mB, mI);
    k_prepw  <<<336, 256, 0, stream>>>(W1,R1,W2,R2,W3,R3,Wr,Rr,Wc,Rc,Wo,Ro,T1,T2,T3,Tr,Tc,To);

    k_conv1  <<<NB_FUSED, 512, 0, stream>>>(rp, mB, mI, x, invd, T1, y1, st1);
    k_conv23 <<<NB_FUSED, 512, 0, stream>>>(rp, mB, mI, y1, invd, st1, g1, be1, T2, T3, y2, y3, st2, st3);
    k_regr   <<<NB_FUSED, 512, 0, stream>>>(rp, mB, mI, y2, invd, st2, g2, be2, Tr, br, out + REG_OFF);
    k_clsobj <<<NB_FUSED, 512, 0, stream>>>(rp, mB, mI, y3, invd, st3, g3, be3, Tc, To, bc, bo, out, out + OBJ_OFF);
}

// Round 7
// 572.414 us; speedup vs baseline: 19.5625x; 1.1956x over previous
//
#include <hip/hip_runtime.h>
#include <hip/hip_bf16.h>

// ---------------- problem constants ----------------
#define NN 30000
#define NE 480000
#define CIN 64
#define KD 1600          // 25*64 spline-K dimension
#define KT 1664          // + 64 root-append columns
#define KSTEPS 26        // K-steps of 64
#define BM 64            // GEMM rows per block
#define NBLK 469         // ceil(30000/64)
#define MROWS (NBLK*BM)  // 30016 (A rows incl. pad)
#define REG_OFF  (30000*101)
#define OBJ_OFF  (30000*105)

typedef short bf16x8 __attribute__((ext_vector_type(8)));
typedef float f32x4  __attribute__((ext_vector_type(4)));

__device__ __forceinline__ ushort f2bf(float x) {
    union { float f; unsigned u; } v; v.f = x;
    unsigned r = v.u + 0x7FFFu + ((v.u >> 16) & 1u);   // RNE
    return (ushort)(r >> 16);
}

// ---------------- graph preprocessing ----------------
__global__ void k_count(const int* __restrict__ dst, int* __restrict__ deg) {
    int e = blockIdx.x * 256 + threadIdx.x;
    if (e < NE) atomicAdd(&deg[dst[e]], 1);
}

__global__ void k_scan(const int* __restrict__ deg, int* __restrict__ rp,
                       int* __restrict__ cur, float* __restrict__ invd) {
    __shared__ int s[1024];
    int t = threadIdx.x;
    const int CH = 30;                       // 1024*30 >= 30000
    int base = t * CH, loc = 0;
    for (int i = 0; i < CH; ++i) { int n = base + i; if (n < NN) loc += deg[n]; }
    s[t] = loc; __syncthreads();
    for (int o = 1; o < 1024; o <<= 1) {
        int v = (t >= o) ? s[t - o] : 0;
        __syncthreads(); s[t] += v; __syncthreads();
    }
    int run = s[t] - loc;                    // exclusive prefix for this chunk
    for (int i = 0; i < CH; ++i) {
        int n = base + i;
        if (n < NN) {
            int dg = deg[n];
            rp[n] = run; cur[n] = run;
            invd[n] = 1.f / (float)(dg > 0 ? dg : 1);
            run += dg;
        }
    }
    if (t == 0) rp[NN] = NE;
}

// spline basis per edge, scattered into dst-sorted order.
// pseudo in [0,1) -> i0,i1 in 0..3 -> corners are k00+{0,1,5,6}.
__global__ void k_scatter(const float* __restrict__ ea, const int* __restrict__ src,
                          const int* __restrict__ dst, int* __restrict__ cur,
                          float4* __restrict__ mB, int2* __restrict__ mI) {
    int e = blockIdx.x * 256 + threadIdx.x;
    if (e >= NE) return;
    float p0 = ea[e*3+0], p1 = ea[e*3+1];
    float v0 = p0*4.f, v1 = p1*4.f;
    float b0 = fminf(fmaxf(floorf(v0),0.f),4.f);
    float b1 = fminf(fmaxf(floorf(v1),0.f),4.f);
    float f0 = v0-b0, f1 = v1-b1;
    int i0 = (int)b0, i1 = (int)b1;
    float B00 = (1.f-f0)*(1.f-f1);
    float B01 = (1.f-f0)*f1;
    float B10 = f0*(1.f-f1);
    float B11 = f0*f1;
    int k00 = i0*5 + i1;
    int dn = dst[e];
    int pos = atomicAdd(&cur[dn], 1);
    mB[pos] = make_float4(B00,B01,B10,B11);
    mI[pos] = make_int2(k00, src[e]);
}

// pack+transpose weights to bf16 [outcol][KT]:
// T1: 64 rows. T23: 128 rows (W2 | W3). Tr: 16 rows (4 valid). TcTo: 128 rows (Wc 112 | Wo 16).
__global__ void k_prepw(const float* W1,const float* R1,const float* W2,const float* R2,
                        const float* W3,const float* R3,const float* Wr,const float* Rr,
                        const float* Wc,const float* Rc,const float* Wo,const float* Ro,
                        ushort* T1, ushort* T23, ushort* Tr, ushort* TcTo) {
    int b = blockIdx.x;
    const float* W; const float* R; ushort* T; int od; int col;
    if      (b < 64)  { W=W1; R=R1; T=T1  + (long)b*KT;       od=64;  col=b;     }
    else if (b < 128) { W=W2; R=R2; T=T23 + (long)(b-64)*KT;  od=64;  col=b-64;  }
    else if (b < 192) { W=W3; R=R3; T=T23 + (long)(b-64)*KT;  od=64;  col=b-128; }
    else if (b < 208) { W=Wr; R=Rr; T=Tr  + (long)(b-192)*KT; od=4;   col=b-192; }
    else if (b < 320) { W=Wc; R=Rc; T=TcTo+ (long)(b-208)*KT; od=101; col=b-208; }
    else              { W=Wo; R=Ro; T=TcTo+ (long)(b-208)*KT; od=1;   col=b-320; }
    for (int kc = threadIdx.x; kc < KT; kc += 256) {
        float v = 0.f;
        if (col < od) v = (kc < KD) ? W[(long)kc*od + col] : R[(long)(kc-KD)*od + col];
        T[kc] = f2bf(v);
    }
}

// ---------------- aggregation: one wave per node, no LDS, no barriers ----------------
#define AGGC(K, A_, B_, C_, D_) case K: A_ += bb.x*xu; B_ += bb.y*xu; C_ += bb.z*xu; D_ += bb.w*xu; break;

template<bool NORM>
__global__ void k_agg(const int* __restrict__ rp, const float4* __restrict__ mB,
                      const int2* __restrict__ mI, const float* __restrict__ f,
                      const float* __restrict__ invd,
                      const float* __restrict__ st, const float* __restrict__ g,
                      const float* __restrict__ be, ushort* __restrict__ A) {
    int wid = (blockIdx.x * 256 + threadIdx.x) >> 6;
    int l = threadIdx.x & 63;
    if (wid >= NN) return;
    float na = 0.f, nc = 0.f;
    if (NORM) {
        const float inv_n = 1.f / (float)NN;
        float mm = st[l] * inv_n;
        float var = st[64 + l] * inv_n - mm * mm;
        float rs = rsqrtf(var + 1e-5f);
        na = g[l] * rs; nc = be[l] - mm * na;
    }
    float a00=0.f,a01=0.f,a02=0.f,a03=0.f,a04=0.f;
    float a05=0.f,a06=0.f,a07=0.f,a08=0.f,a09=0.f;
    float a10=0.f,a11=0.f,a12=0.f,a13=0.f,a14=0.f;
    float a15=0.f,a16=0.f,a17=0.f,a18=0.f,a19=0.f;
    float a20=0.f,a21=0.f,a22=0.f,a23=0.f,a24=0.f;
    int beg = rp[wid], end = rp[wid + 1];
    for (int e0 = beg; e0 < end; e0 += 8) {
        float4 b[8]; int2 m[8]; float xv[8];
        #pragma unroll
        for (int u = 0; u < 8; ++u) {
            int e = e0 + u;
            bool valid = e < end;
            int ee = valid ? e : beg;
            b[u] = mB[ee]; m[u] = mI[ee];
            if (!valid) b[u] = make_float4(0,0,0,0);
        }
        #pragma unroll
        for (int u = 0; u < 8; ++u) {
            float v = f[(long)m[u].y * CIN + l];
            if (NORM) v = fmaxf(v * na + nc, 0.f);
            xv[u] = v;
        }
        #pragma unroll
        for (int u = 0; u < 8; ++u) {
            int k00 = __builtin_amdgcn_readfirstlane(m[u].x);
            float4 bb = b[u]; float xu = xv[u];
            switch (k00) {
                AGGC(0,  a00,a01,a05,a06)
                AGGC(1,  a01,a02,a06,a07)
                AGGC(2,  a02,a03,a07,a08)
                AGGC(3,  a03,a04,a08,a09)
                AGGC(5,  a05,a06,a10,a11)
                AGGC(6,  a06,a07,a11,a12)
                AGGC(7,  a07,a08,a12,a13)
                AGGC(8,  a08,a09,a13,a14)
                AGGC(10, a10,a11,a15,a16)
                AGGC(11, a11,a12,a16,a17)
                AGGC(12, a12,a13,a17,a18)
                AGGC(13, a13,a14,a18,a19)
                AGGC(15, a15,a16,a20,a21)
                AGGC(16, a16,a17,a21,a22)
                AGGC(17, a17,a18,a22,a23)
                AGGC(18, a18,a19,a23,a24)
                default: break;
            }
        }
    }
    float s = invd[wid];
    ushort* rb = A + (long)wid * KT + l;
    #define STO(K, V) rb[K*CIN] = f2bf((V) * s);
    STO(0,a00)  STO(1,a01)  STO(2,a02)  STO(3,a03)  STO(4,a04)
    STO(5,a05)  STO(6,a06)  STO(7,a07)  STO(8,a08)  STO(9,a09)
    STO(10,a10) STO(11,a11) STO(12,a12) STO(13,a13) STO(14,a14)
    STO(15,a15) STO(16,a16) STO(17,a17) STO(18,a18) STO(19,a19)
    STO(20,a20) STO(21,a21) STO(22,a22) STO(23,a23) STO(24,a24)
    #undef STO
    float rv = f[(long)wid * CIN + l];
    if (NORM) rv = fmaxf(rv * na + nc, 0.f);
    rb[KD] = f2bf(rv);
}

// ---------------- GEMM: A[30016 x 1664] bf16 x B[N x 1664] bf16 -> f32 ----------------
// BM=64 rows/block, 512 threads (8 waves). A staged to LDS double-buffered:
// pre-swizzled global source + LINEAR ds_write (conflict-free) + XOR-swizzled ds_read.
// B-fragments from global (L2-resident), amortized over 4 M-frags.
// MODE 0: N=64  (T1)  -> y1 + st1, K-split 2 (wave-halves), no bias
// MODE 1: N=128 (T23) -> waves 0-3: y2+st2, waves 4-7: y3+st3
// MODE 2: N=16  (Tr)  -> out stride 4 (4 valid cols), K-split 8, bias
// MODE 3: N=128 (TcTo)-> waves 0-6: cls (101 valid, stride 101, bias), wave 7: obj (1 col, bias)
template<int MODE>
__global__ void k_gemm(const ushort* __restrict__ A, const ushort* __restrict__ B,
                       float* __restrict__ o0, float* __restrict__ o1,
                       float* __restrict__ s0, float* __restrict__ s1,
                       const float* __restrict__ b0, const float* __restrict__ b1) {
    constexpr int PARTQ = (MODE == 0) ? 1024 : (MODE == 2 ? 1792 : 1);
    __shared__ ushort As[2 * 4096];          // 2 x 8KB
    __shared__ f32x4 part[PARTQ];
    const int tid = threadIdx.x, w = tid >> 6, l = tid & 63;
    const int m0 = blockIdx.x * BM;

    int colrow;
    if constexpr (MODE == 0)      colrow = ((w & 3) << 4) + (l & 15);
    else if constexpr (MODE == 2) colrow = (l & 15);
    else                          colrow = (w << 4) + (l & 15);
    const ushort* Bp = B + (long)colrow * KT + ((l >> 4) << 3);

    const int srow = tid >> 3, sj = tid & 7;
    const ushort* Asrc = A + (long)(m0 + srow) * KT + ((sj ^ (srow & 7)) << 3);

    f32x4 acc[4];
    #pragma unroll
    for (int m = 0; m < 4; ++m) acc[m] = (f32x4){0.f,0.f,0.f,0.f};

    // prologue: stage K-step 0 into buf 0
    int4 v0 = *(const int4*)(Asrc);
    *(int4*)((char*)As + tid * 16) = v0;
    __syncthreads();

    int buf = 0;
    for (int ks = 0; ks < KSTEPS; ++ks) {
        int4 vn;
        if (ks < KSTEPS - 1) vn = *(const int4*)(Asrc + (ks + 1) * 64);
        bool act;
        if constexpr (MODE == 0)      act = (w < 4) ? (ks < 13) : (ks >= 13);
        else if constexpr (MODE == 2) act = ((ks & 7) == w);
        else                          act = true;
        if (act) {
            bf16x8 bb0 = *(const bf16x8*)(Bp + ks * 64);
            bf16x8 bb1 = *(const bf16x8*)(Bp + ks * 64 + 32);
            const char* Ab = (const char*)As + buf * 8192;
            #pragma unroll
            for (int m = 0; m < 4; ++m) {
                int r = (m << 4) + (l & 15);
                int j0 = (l >> 4);
                bf16x8 a = *(const bf16x8*)(Ab + r * 128 + ((j0 ^ (r & 7)) << 4));
                acc[m] = __builtin_amdgcn_mfma_f32_16x16x32_bf16(a, bb0, acc[m], 0, 0, 0);
            }
            #pragma unroll
            for (int m = 0; m < 4; ++m) {
                int r = (m << 4) + (l & 15);
                int j1 = 4 + (l >> 4);
                bf16x8 a = *(const bf16x8*)(Ab + r * 128 + ((j1 ^ (r & 7)) << 4));
                acc[m] = __builtin_amdgcn_mfma_f32_16x16x32_bf16(a, bb1, acc[m], 0, 0, 0);
            }
        }
        if (ks < KSTEPS - 1) *(int4*)((char*)As + (buf ^ 1) * 8192 + tid * 16) = vn;
        __syncthreads();
        buf ^= 1;
    }

    // ---- epilogue ----
    auto emit = [&](f32x4* ac, float* out, int ostride, int col, int odcap, float bv, float* stats) {
        float p1 = 0.f, p2 = 0.f;
        #pragma unroll
        for (int m = 0; m < 4; ++m) {
            #pragma unroll
            for (int r = 0; r < 4; ++r) {
                int row = m0 + (m << 4) + ((l >> 4) << 2) + r;
                if (row < NN) {
                    float v = ac[m][r] + bv;
                    if (col < odcap) out[(long)row * ostride + col] = v;
                    p1 += v; p2 += v * v;
                }
            }
        }
        if (stats) {
            p1 += __shfl_down(p1, 32); p2 += __shfl_down(p2, 32);
            p1 += __shfl_down(p1, 16); p2 += __shfl_down(p2, 16);
            if (l < 16) { atomicAdd(&stats[col], p1); atomicAdd(&stats[64 + col], p2); }
        }
    };

    if constexpr (MODE == 0) {
        if (w >= 4) {
            #pragma unroll
            for (int m = 0; m < 4; ++m) part[((w & 3) << 8) + (l << 2) + m] = acc[m];
        }
        __syncthreads();
        if (w < 4) {
            #pragma unroll
            for (int m = 0; m < 4; ++m) acc[m] += part[((w & 3) << 8) + (l << 2) + m];
            emit(acc, o0, 64, ((w & 3) << 4) + (l & 15), 64, 0.f, s0);
        }
    } else if constexpr (MODE == 1) {
        if (w < 4) emit(acc, o0, 64, (w << 4) + (l & 15), 64, 0.f, s0);
        else       emit(acc, o1, 64, ((w - 4) << 4) + (l & 15), 64, 0.f, s1);
    } else if constexpr (MODE == 2) {
        if (w > 0) {
            #pragma unroll
            for (int m = 0; m < 4; ++m) part[((w - 1) << 8) + (l << 2) + m] = acc[m];
        }
        __syncthreads();
        if (w == 0) {
            for (int i = 0; i < 7; ++i) {
                #pragma unroll
                for (int m = 0; m < 4; ++m) acc[m] += part[(i << 8) + (l << 2) + m];
            }
            int col = l & 15;
            emit(acc, o0, 4, col, 4, (col < 4) ? b0[col] : 0.f, nullptr);
        }
    } else {
        if (w < 7) {
            int col = (w << 4) + (l & 15);
            emit(acc, o0, 101, col, 101, (col < 101) ? b0[col] : 0.f, nullptr);
        } else {
            int col = l & 15;
            emit(acc, o1, 1, col, 1, b1[0], nullptr);
        }
    }
}

// ---------------- host launch ----------------
extern "C" void kernel_launch(void* const* d_in, const int* in_sizes, int n_in,
                              void* d_out, int out_size, void* d_ws, size_t ws_size,
                              hipStream_t stream) {
    const float* x    = (const float*)d_in[0];
    const float* ea   = (const float*)d_in[1];
    const int*   src  = (const int*)d_in[2];
    const int*   dst  = (const int*)d_in[3];
    const float* W1   = (const float*)d_in[4];
    const float* R1   = (const float*)d_in[5];
    const float* g1   = (const float*)d_in[6];
    const float* be1  = (const float*)d_in[7];
    const float* W2   = (const float*)d_in[8];
    const float* R2   = (const float*)d_in[9];
    const float* g2   = (const float*)d_in[10];
    const float* be2  = (const float*)d_in[11];
    const float* W3   = (const float*)d_in[12];
    const float* R3   = (const float*)d_in[13];
    const float* g3   = (const float*)d_in[14];
    const float* be3  = (const float*)d_in[15];
    const float* Wr   = (const float*)d_in[16];
    const float* Rr   = (const float*)d_in[17];
    const float* br   = (const float*)d_in[18];
    const float* Wc   = (const float*)d_in[19];
    const float* Rc   = (const float*)d_in[20];
    const float* bc   = (const float*)d_in[21];
    const float* Wo   = (const float*)d_in[22];
    const float* Ro   = (const float*)d_in[23];
    const float* bo   = (const float*)d_in[24];
    float* out = (float*)d_out;

    char* p = (char*)d_ws;
    auto alloc = [&](size_t bytes) { char* r = p; p += (bytes + 255) & ~(size_t)255; return r; };
    float4* mB   = (float4*)alloc((size_t)NE * 16);
    int2*   mI   = (int2*)  alloc((size_t)NE * 8);
    int*    deg  = (int*)   alloc((size_t)NN * 4);
    int*    rp   = (int*)   alloc((size_t)(NN + 1) * 4);
    int*    cur  = (int*)   alloc((size_t)NN * 4);
    float*  invd = (float*) alloc((size_t)NN * 4);
    ushort* T1   = (ushort*)alloc((size_t)64  * KT * 2);
    ushort* T23  = (ushort*)alloc((size_t)128 * KT * 2);
    ushort* Tr   = (ushort*)alloc((size_t)16  * KT * 2);
    ushort* TcTo = (ushort*)alloc((size_t)128 * KT * 2);
    float*  y1   = (float*) alloc((size_t)NN * CIN * 4);
    float*  y2   = (float*) alloc((size_t)NN * CIN * 4);
    float*  y3   = (float*) alloc((size_t)NN * CIN * 4);
    float*  stats= (float*) alloc(3 * 128 * 4);
    ushort* A    = (ushort*)alloc((size_t)MROWS * KT * 2);   // ~99.9 MB
    float* st1 = stats, *st2 = stats + 128, *st3 = stats + 256;

    hipMemsetAsync(deg, 0, (size_t)NN * 4, stream);
    hipMemsetAsync(stats, 0, 3 * 128 * 4, stream);

    k_count  <<<1875, 256, 0, stream>>>(dst, deg);
    k_scan   <<<1, 1024, 0, stream>>>(deg, rp, cur, invd);
    k_scatter<<<1875, 256, 0, stream>>>(ea, src, dst, cur, mB, mI);
    k_prepw  <<<336, 256, 0, stream>>>(W1,R1,W2,R2,W3,R3,Wr,Rr,Wc,Rc,Wo,Ro,T1,T23,Tr,TcTo);

    // conv1
    k_agg<false><<<7500, 256, 0, stream>>>(rp, mB, mI, x, invd, nullptr, nullptr, nullptr, A);
    k_gemm<0><<<NBLK, 512, 0, stream>>>(A, T1, y1, nullptr, st1, nullptr, nullptr, nullptr);
    // conv2 + conv3 (shared aggregation of BN1(y1))
    k_agg<true><<<7500, 256, 0, stream>>>(rp, mB, mI, y1, invd, st1, g1, be1, A);
    k_gemm<1><<<NBLK, 512, 0, stream>>>(A, T23, y2, y3, st2, st3, nullptr, nullptr);
    // regr head on BN2(y2)
    k_agg<true><<<7500, 256, 0, stream>>>(rp, mB, mI, y2, invd, st2, g2, be2, A);
    k_gemm<2><<<NBLK, 512, 0, stream>>>(A, Tr, out + REG_OFF, nullptr, nullptr, nullptr, br, nullptr);
    // cls + obj heads on BN3(y3)
    k_agg<true><<<7500, 256, 0, stream>>>(rp, mB, mI, y3, invd, st3, g3, be3, A);
    k_gemm<3><<<NBLK, 512, 0, stream>>>(A, TcTo, out, out + OBJ_OFF, nullptr, nullptr, bc, bo);
}

// Round 8
// 465.150 us; speedup vs baseline: 24.0736x; 1.2306x over previous
//
#include <hip/hip_runtime.h>
#include <hip/hip_bf16.h>

// ---------------- problem constants ----------------
#define NN 30000
#define NE 480000
#define CIN 64
#define KD 1600          // 25*64 spline-K dimension
#define KT 1664          // + 64 root-append columns
#define KMAC 13          // K macro-steps of 128
#define BM 64            // GEMM rows per block
#define NBLK 469         // ceil(30000/64)
#define MROWS (NBLK*BM)  // 30016 (A rows incl. pad)
#define REG_OFF  (30000*101)
#define OBJ_OFF  (30000*105)

typedef short bf16x8 __attribute__((ext_vector_type(8)));
typedef float f32x4  __attribute__((ext_vector_type(4)));

__device__ __forceinline__ ushort f2bf(float x) {
    union { float f; unsigned u; } v; v.f = x;
    unsigned r = v.u + 0x7FFFu + ((v.u >> 16) & 1u);   // RNE
    return (ushort)(r >> 16);
}

// ---------------- graph preprocessing ----------------
__global__ void k_count(const int* __restrict__ dst, int* __restrict__ deg) {
    int e = blockIdx.x * 256 + threadIdx.x;
    if (e < NE) atomicAdd(&deg[dst[e]], 1);
}

__global__ void k_scan(const int* __restrict__ deg, int* __restrict__ rp,
                       int* __restrict__ cur, float* __restrict__ invd) {
    __shared__ int s[1024];
    int t = threadIdx.x;
    const int CH = 30;                       // 1024*30 >= 30000
    int base = t * CH, loc = 0;
    for (int i = 0; i < CH; ++i) { int n = base + i; if (n < NN) loc += deg[n]; }
    s[t] = loc; __syncthreads();
    for (int o = 1; o < 1024; o <<= 1) {
        int v = (t >= o) ? s[t - o] : 0;
        __syncthreads(); s[t] += v; __syncthreads();
    }
    int run = s[t] - loc;                    // exclusive prefix for this chunk
    for (int i = 0; i < CH; ++i) {
        int n = base + i;
        if (n < NN) {
            int dg = deg[n];
            rp[n] = run; cur[n] = run;
            invd[n] = 1.f / (float)(dg > 0 ? dg : 1);
            run += dg;
        }
    }
    if (t == 0) rp[NN] = NE;
}

// spline basis per edge, scattered into dst-sorted order.
// pseudo in [0,1) -> i0,i1 in 0..3 -> corners are k00+{0,1,5,6}.
__global__ void k_scatter(const float* __restrict__ ea, const int* __restrict__ src,
                          const int* __restrict__ dst, int* __restrict__ cur,
                          float4* __restrict__ mB, int2* __restrict__ mI) {
    int e = blockIdx.x * 256 + threadIdx.x;
    if (e >= NE) return;
    float p0 = ea[e*3+0], p1 = ea[e*3+1];
    float v0 = p0*4.f, v1 = p1*4.f;
    float b0 = fminf(fmaxf(floorf(v0),0.f),4.f);
    float b1 = fminf(fmaxf(floorf(v1),0.f),4.f);
    float f0 = v0-b0, f1 = v1-b1;
    int i0 = (int)b0, i1 = (int)b1;
    float B00 = (1.f-f0)*(1.f-f1);
    float B01 = (1.f-f0)*f1;
    float B10 = f0*(1.f-f1);
    float B11 = f0*f1;
    int k00 = i0*5 + i1;
    int dn = dst[e];
    int pos = atomicAdd(&cur[dn], 1);
    mB[pos] = make_float4(B00,B01,B10,B11);
    mI[pos] = make_int2(k00, src[e]);
}

// pack+transpose weights to bf16 [outcol][KT]:
// T1: 64 rows. T23: 128 rows (W2 | W3). Tr: 16 rows (4 valid). TcTo: 128 rows (Wc 112 | Wo 16).
__global__ void k_prepw(const float* W1,const float* R1,const float* W2,const float* R2,
                        const float* W3,const float* R3,const float* Wr,const float* Rr,
                        const float* Wc,const float* Rc,const float* Wo,const float* Ro,
                        ushort* T1, ushort* T23, ushort* Tr, ushort* TcTo) {
    int b = blockIdx.x;
    const float* W; const float* R; ushort* T; int od; int col;
    if      (b < 64)  { W=W1; R=R1; T=T1  + (long)b*KT;       od=64;  col=b;     }
    else if (b < 128) { W=W2; R=R2; T=T23 + (long)(b-64)*KT;  od=64;  col=b-64;  }
    else if (b < 192) { W=W3; R=R3; T=T23 + (long)(b-64)*KT;  od=64;  col=b-128; }
    else if (b < 208) { W=Wr; R=Rr; T=Tr  + (long)(b-192)*KT; od=4;   col=b-192; }
    else if (b < 320) { W=Wc; R=Rc; T=TcTo+ (long)(b-208)*KT; od=101; col=b-208; }
    else              { W=Wo; R=Ro; T=TcTo+ (long)(b-208)*KT; od=1;   col=b-320; }
    for (int kc = threadIdx.x; kc < KT; kc += 256) {
        float v = 0.f;
        if (col < od) v = (kc < KD) ? W[(long)kc*od + col] : R[(long)(kc-KD)*od + col];
        T[kc] = f2bf(v);
    }
}

// ---------------- aggregation: one wave per node, phase-split for MLP ----------------
#define AGGC(K, A_, B_, C_, D_) case K: A_ += bb.x*xu; B_ += bb.y*xu; C_ += bb.z*xu; D_ += bb.w*xu; break;

template<bool NORM>
__global__ void k_agg(const int* __restrict__ rp, const float4* __restrict__ mB,
                      const int2* __restrict__ mI, const float* __restrict__ f,
                      const float* __restrict__ invd,
                      const float* __restrict__ st, const float* __restrict__ g,
                      const float* __restrict__ be, ushort* __restrict__ A) {
    int wid = (blockIdx.x * 256 + threadIdx.x) >> 6;
    wid = __builtin_amdgcn_readfirstlane(wid);   // wave-uniform -> scalar loads for rp/mI/mB
    int l = threadIdx.x & 63;
    if (wid >= NN) return;
    float na = 0.f, nc = 0.f;
    if (NORM) {
        const float inv_n = 1.f / (float)NN;
        float mm = st[l] * inv_n;
        float var = st[64 + l] * inv_n - mm * mm;
        float rs = rsqrtf(var + 1e-5f);
        na = g[l] * rs; nc = be[l] - mm * na;
    }
    float a00=0.f,a01=0.f,a02=0.f,a03=0.f,a04=0.f;
    float a05=0.f,a06=0.f,a07=0.f,a08=0.f,a09=0.f;
    float a10=0.f,a11=0.f,a12=0.f,a13=0.f,a14=0.f;
    float a15=0.f,a16=0.f,a17=0.f,a18=0.f,a19=0.f;
    float a20=0.f,a21=0.f,a22=0.f,a23=0.f,a24=0.f;
    int beg = rp[wid], end = rp[wid + 1];
    for (int e0 = beg; e0 < end; e0 += 8) {
        // phase 1: edge metadata (uniform -> SMEM path)
        int2 m[8];
        #pragma unroll
        for (int u = 0; u < 8; ++u) {
            int e = e0 + u;
            m[u] = mI[(e < end) ? e : beg];
        }
        // phase 2: issue ALL 8 gathers before any consumption
        float xv[8];
        #pragma unroll
        for (int u = 0; u < 8; ++u) xv[u] = f[(long)m[u].y * CIN + l];
        __builtin_amdgcn_sched_barrier(0);
        // phase 3: basis weights (uniform -> SMEM path), zero the tail
        float4 b[8];
        #pragma unroll
        for (int u = 0; u < 8; ++u) {
            int e = e0 + u;
            b[u] = mB[(e < end) ? e : beg];
            if (e >= end) b[u] = make_float4(0,0,0,0);
        }
        __builtin_amdgcn_sched_barrier(0);
        // phase 4: consume
        #pragma unroll
        for (int u = 0; u < 8; ++u) {
            float xu = xv[u];
            if (NORM) xu = fmaxf(xu * na + nc, 0.f);
            int k00 = __builtin_amdgcn_readfirstlane(m[u].x);
            float4 bb = b[u];
            switch (k00) {
                AGGC(0,  a00,a01,a05,a06)
                AGGC(1,  a01,a02,a06,a07)
                AGGC(2,  a02,a03,a07,a08)
                AGGC(3,  a03,a04,a08,a09)
                AGGC(5,  a05,a06,a10,a11)
                AGGC(6,  a06,a07,a11,a12)
                AGGC(7,  a07,a08,a12,a13)
                AGGC(8,  a08,a09,a13,a14)
                AGGC(10, a10,a11,a15,a16)
                AGGC(11, a11,a12,a16,a17)
                AGGC(12, a12,a13,a17,a18)
                AGGC(13, a13,a14,a18,a19)
                AGGC(15, a15,a16,a20,a21)
                AGGC(16, a16,a17,a21,a22)
                AGGC(17, a17,a18,a22,a23)
                AGGC(18, a18,a19,a23,a24)
                default: break;
            }
        }
    }
    float s = invd[wid];
    ushort* rb = A + (long)wid * KT + l;
    #define STO(K, V) rb[K*CIN] = f2bf((V) * s);
    STO(0,a00)  STO(1,a01)  STO(2,a02)  STO(3,a03)  STO(4,a04)
    STO(5,a05)  STO(6,a06)  STO(7,a07)  STO(8,a08)  STO(9,a09)
    STO(10,a10) STO(11,a11) STO(12,a12) STO(13,a13) STO(14,a14)
    STO(15,a15) STO(16,a16) STO(17,a17) STO(18,a18) STO(19,a19)
    STO(20,a20) STO(21,a21) STO(22,a22) STO(23,a23) STO(24,a24)
    #undef STO
    float rv = f[(long)wid * CIN + l];
    if (NORM) rv = fmaxf(rv * na + nc, 0.f);
    rb[KD] = f2bf(rv);
}

// ---------------- GEMM: A[30016 x 1664] bf16 x B[N x 1664] bf16 -> f32 ----------------
// BM=64 rows/block, 512 threads (8 waves), BK=128 (13 macro-steps, one barrier pair each).
// A double-buffered in LDS (32 KB): XOR-swizzled ds_write + matching ds_read, conflict-free.
// B-fragments from global (L2-resident), 1 load per 4 MFMA.
// MODE 0: N=64  (T1)  -> y1 + st1, K-split [0,7)/[7,13), no bias
// MODE 1: N=128 (T23) -> waves 0-3: y2+st2, waves 4-7: y3+st3
// MODE 2: N=16  (Tr)  -> out stride 4 (4 valid cols), K round-robin, bias
// MODE 3: N=128 (TcTo)-> waves 0-6: cls (101 valid, stride 101, bias), wave 7: obj (1 col, bias)
template<int MODE>
__global__ void k_gemm(const ushort* __restrict__ A, const ushort* __restrict__ B,
                       float* __restrict__ o0, float* __restrict__ o1,
                       float* __restrict__ s0, float* __restrict__ s1,
                       const float* __restrict__ b0, const float* __restrict__ b1) {
    __shared__ ushort As[2 * 8192];           // 2 x 16 KB
    f32x4* part = (f32x4*)As;                 // epilogue overlay (As dead by then)
    const int tid = threadIdx.x, w = tid >> 6, l = tid & 63;
    const int m0 = blockIdx.x * BM;

    int colrow;
    if constexpr (MODE == 0)      colrow = ((w & 3) << 4) + (l & 15);
    else if constexpr (MODE == 2) colrow = (l & 15);
    else                          colrow = (w << 4) + (l & 15);
    const ushort* Bp = B + (long)colrow * KT + ((l >> 4) << 3);

    // staging map: chunk c = tid (+512); row = c>>4 (c<512: 0..31; +512: 32..63), j = c&15
    const int r0 = tid >> 4, j0 = tid & 15;
    const ushort* Asrc0 = A + (long)(m0 + r0) * KT + (j0 << 3);
    const ushort* Asrc1 = A + (long)(m0 + 32 + r0) * KT + (j0 << 3);
    const int swzo = ((j0 ^ (r0 & 7)) << 4);  // (32+r0)&7 == r0&7

    f32x4 acc[4];
    #pragma unroll
    for (int m = 0; m < 4; ++m) acc[m] = (f32x4){0.f,0.f,0.f,0.f};

    // prologue: stage macro-step 0 into buf 0
    {
        int4 v0 = *(const int4*)(Asrc0);
        int4 v1 = *(const int4*)(Asrc1);
        char* basep = (char*)As;
        *(int4*)(basep + r0 * 256 + swzo) = v0;
        *(int4*)(basep + (32 + r0) * 256 + swzo) = v1;
    }
    __syncthreads();

    int buf = 0;
    for (int ks = 0; ks < KMAC; ++ks) {
        int4 v0, v1;
        if (ks < KMAC - 1) {
            v0 = *(const int4*)(Asrc0 + (ks + 1) * 128);
            v1 = *(const int4*)(Asrc1 + (ks + 1) * 128);
        }
        bool act;
        if constexpr (MODE == 0)      act = (w < 4) ? (ks < 7) : (ks >= 7);
        else if constexpr (MODE == 2) act = ((ks & 7) == w);
        else                          act = true;
        if (act) {
            const char* Ab = (const char*)As + buf * 16384;
            #pragma unroll
            for (int s = 0; s < 4; ++s) {
                bf16x8 bb = *(const bf16x8*)(Bp + ks * 128 + s * 32);
                #pragma unroll
                for (int m = 0; m < 4; ++m) {
                    int r = (m << 4) + (l & 15);
                    int j = (s << 2) + (l >> 4);
                    bf16x8 a = *(const bf16x8*)(Ab + r * 256 + ((j ^ (r & 7)) << 4));
                    acc[m] = __builtin_amdgcn_mfma_f32_16x16x32_bf16(a, bb, acc[m], 0, 0, 0);
                }
            }
        }
        if (ks < KMAC - 1) {
            char* basep = (char*)As + (buf ^ 1) * 16384;
            *(int4*)(basep + r0 * 256 + swzo) = v0;
            *(int4*)(basep + (32 + r0) * 256 + swzo) = v1;
        }
        __syncthreads();
        buf ^= 1;
    }

    // ---- epilogue (part[] overlays As; all As reads completed before final barrier) ----
    auto emit = [&](f32x4* ac, float* out, int ostride, int col, int odcap, float bv, float* stats) {
        float p1 = 0.f, p2 = 0.f;
        #pragma unroll
        for (int m = 0; m < 4; ++m) {
            #pragma unroll
            for (int r = 0; r < 4; ++r) {
                int row = m0 + (m << 4) + ((l >> 4) << 2) + r;
                if (row < NN) {
                    float v = ac[m][r] + bv;
                    if (col < odcap) out[(long)row * ostride + col] = v;
                    p1 += v; p2 += v * v;
                }
            }
        }
        if (stats) {
            p1 += __shfl_down(p1, 32); p2 += __shfl_down(p2, 32);
            p1 += __shfl_down(p1, 16); p2 += __shfl_down(p2, 16);
            if (l < 16) { atomicAdd(&stats[col], p1); atomicAdd(&stats[64 + col], p2); }
        }
    };

    if constexpr (MODE == 0) {
        if (w >= 4) {
            #pragma unroll
            for (int m = 0; m < 4; ++m) part[((w & 3) << 8) + (l << 2) + m] = acc[m];
        }
        __syncthreads();
        if (w < 4) {
            #pragma unroll
            for (int m = 0; m < 4; ++m) acc[m] += part[((w & 3) << 8) + (l << 2) + m];
            emit(acc, o0, 64, ((w & 3) << 4) + (l & 15), 64, 0.f, s0);
        }
    } else if constexpr (MODE == 1) {
        if (w < 4) emit(acc, o0, 64, (w << 4) + (l & 15), 64, 0.f, s0);
        else       emit(acc, o1, 64, ((w - 4) << 4) + (l & 15), 64, 0.f, s1);
    } else if constexpr (MODE == 2) {
        if (w > 0) {
            #pragma unroll
            for (int m = 0; m < 4; ++m) part[((w - 1) << 8) + (l << 2) + m] = acc[m];
        }
        __syncthreads();
        if (w == 0) {
            for (int i = 0; i < 7; ++i) {
                #pragma unroll
                for (int m = 0; m < 4; ++m) acc[m] += part[(i << 8) + (l << 2) + m];
            }
            int col = l & 15;
            emit(acc, o0, 4, col, 4, (col < 4) ? b0[col] : 0.f, nullptr);
        }
    } else {
        if (w < 7) {
            int col = (w << 4) + (l & 15);
            emit(acc, o0, 101, col, 101, (col < 101) ? b0[col] : 0.f, nullptr);
        } else {
            int col = l & 15;
            emit(acc, o1, 1, col, 1, b1[0], nullptr);
        }
    }
}

// ---------------- host launch ----------------
extern "C" void kernel_launch(void* const* d_in, const int* in_sizes, int n_in,
                              void* d_out, int out_size, void* d_ws, size_t ws_size,
                              hipStream_t stream) {
    const float* x    = (const float*)d_in[0];
    const float* ea   = (const float*)d_in[1];
    const int*   src  = (const int*)d_in[2];
    const int*   dst  = (const int*)d_in[3];
    const float* W1   = (const float*)d_in[4];
    const float* R1   = (const float*)d_in[5];
    const float* g1   = (const float*)d_in[6];
    const float* be1  = (const float*)d_in[7];
    const float* W2   = (const float*)d_in[8];
    const float* R2   = (const float*)d_in[9];
    const float* g2   = (const float*)d_in[10];
    const float* be2  = (const float*)d_in[11];
    const float* W3   = (const float*)d_in[12];
    const float* R3   = (const float*)d_in[13];
    const float* g3   = (const float*)d_in[14];
    const float* be3  = (const float*)d_in[15];
    const float* Wr   = (const float*)d_in[16];
    const float* Rr   = (const float*)d_in[17];
    const float* br   = (const float*)d_in[18];
    const float* Wc   = (const float*)d_in[19];
    const float* Rc   = (const float*)d_in[20];
    const float* bc   = (const float*)d_in[21];
    const float* Wo   = (const float*)d_in[22];
    const float* Ro   = (const float*)d_in[23];
    const float* bo   = (const float*)d_in[24];
    float* out = (float*)d_out;

    char* p = (char*)d_ws;
    auto alloc = [&](size_t bytes) { char* r = p; p += (bytes + 255) & ~(size_t)255; return r; };
    float4* mB   = (float4*)alloc((size_t)NE * 16);
    int2*   mI   = (int2*)  alloc((size_t)NE * 8);
    int*    deg  = (int*)   alloc((size_t)NN * 4);
    int*    rp   = (int*)   alloc((size_t)(NN + 1) * 4);
    int*    cur  = (int*)   alloc((size_t)NN * 4);
    float*  invd = (float*) alloc((size_t)NN * 4);
    ushort* T1   = (ushort*)alloc((size_t)64  * KT * 2);
    ushort* T23  = (ushort*)alloc((size_t)128 * KT * 2);
    ushort* Tr   = (ushort*)alloc((size_t)16  * KT * 2);
    ushort* TcTo = (ushort*)alloc((size_t)128 * KT * 2);
    float*  y1   = (float*) alloc((size_t)NN * CIN * 4);
    float*  y2   = (float*) alloc((size_t)NN * CIN * 4);
    float*  y3   = (float*) alloc((size_t)NN * CIN * 4);
    float*  stats= (float*) alloc(3 * 128 * 4);
    ushort* A    = (ushort*)alloc((size_t)MROWS * KT * 2);   // ~99.9 MB
    float* st1 = stats, *st2 = stats + 128, *st3 = stats + 256;

    hipMemsetAsync(deg, 0, (size_t)NN * 4, stream);
    hipMemsetAsync(stats, 0, 3 * 128 * 4, stream);

    k_count  <<<1875, 256, 0, stream>>>(dst, deg);
    k_scan   <<<1, 1024, 0, stream>>>(deg, rp, cur, invd);
    k_scatter<<<1875, 256, 0, stream>>>(ea, src, dst, cur, mB, mI);
    k_prepw  <<<336, 256, 0, stream>>>(W1,R1,W2,R2,W3,R3,Wr,Rr,Wc,Rc,Wo,Ro,T1,T23,Tr,TcTo);

    // conv1
    k_agg<false><<<7500, 256, 0, stream>>>(rp, mB, mI, x, invd, nullptr, nullptr, nullptr, A);
    k_gemm<0><<<NBLK, 512, 0, stream>>>(A, T1, y1, nullptr, st1, nullptr, nullptr, nullptr);
    // conv2 + conv3 (shared aggregation of BN1(y1))
    k_agg<true><<<7500, 256, 0, stream>>>(rp, mB, mI, y1, invd, st1, g1, be1, A);
    k_gemm<1><<<NBLK, 512, 0, stream>>>(A, T23, y2, y3, st2, st3, nullptr, nullptr);
    // regr head on BN2(y2)
    k_agg<true><<<7500, 256, 0, stream>>>(rp, mB, mI, y2, invd, st2, g2, be2, A);
    k_gemm<2><<<NBLK, 512, 0, stream>>>(A, Tr, out + REG_OFF, nullptr, nullptr, nullptr, br, nullptr);
    // cls + obj heads on BN3(y3)
    k_agg<true><<<7500, 256, 0, stream>>>(rp, mB, mI, y3, invd, st3, g3, be3, A);
    k_gemm<3><<<NBLK, 512, 0, stream>>>(A, TcTo, out, out + OBJ_OFF, nullptr, nullptr, bc, bo);
}

// Round 9
// 450.171 us; speedup vs baseline: 24.8746x; 1.0333x over previous
//
#include <hip/hip_runtime.h>
#include <hip/hip_bf16.h>

// ---------------- problem constants ----------------
#define NN 30000
#define NE 480000
#define CIN 64
#define KD 1600          // 25*64 spline-K dimension
#define KT 1664          // + 64 root-append columns
#define KMAC 13          // K macro-steps of 128
#define BM 32            // GEMM rows per block
#define NBLK 938         // ceil(30000/32)
#define MROWS (NBLK*BM)  // 30016 (A rows incl. pad)
#define NBS 118          // scan blocks: ceil(30000/256)
#define REG_OFF  (30000*101)
#define OBJ_OFF  (30000*105)

typedef short bf16x8 __attribute__((ext_vector_type(8)));
typedef float f32x4  __attribute__((ext_vector_type(4)));

__device__ __forceinline__ ushort f2bf(float x) {
    union { float f; unsigned u; } v; v.f = x;
    unsigned r = v.u + 0x7FFFu + ((v.u >> 16) & 1u);   // RNE
    return (ushort)(r >> 16);
}

// ---------------- graph preprocessing ----------------
__global__ void k_count(const int* __restrict__ dst, int* __restrict__ deg) {
    int e = blockIdx.x * 256 + threadIdx.x;
    if (e < NE) atomicAdd(&deg[dst[e]], 1);
}

// 3-stage parallel exclusive scan of deg[30000] -> rp/cur/invd
__global__ void k_scan1(const int* __restrict__ deg, int* __restrict__ bsum) {
    __shared__ int sred[4];
    int i = blockIdx.x * 256 + threadIdx.x;
    int v = (i < NN) ? deg[i] : 0;
    #pragma unroll
    for (int o = 32; o >= 1; o >>= 1) v += __shfl_down(v, o);
    int w = threadIdx.x >> 6, l = threadIdx.x & 63;
    if (l == 0) sred[w] = v;
    __syncthreads();
    if (threadIdx.x == 0) bsum[blockIdx.x] = sred[0] + sred[1] + sred[2] + sred[3];
}

__global__ void k_scan2(const int* __restrict__ bsum, int* __restrict__ boff) {
    __shared__ int s[128];
    int t = threadIdx.x;
    int v = (t < NBS) ? bsum[t] : 0;
    s[t] = v; __syncthreads();
    for (int o = 1; o < 128; o <<= 1) {
        int u = (t >= o) ? s[t - o] : 0;
        __syncthreads(); s[t] += u; __syncthreads();
    }
    if (t < NBS) boff[t] = s[t] - v;          // exclusive block offset
}

__global__ void k_scan3(const int* __restrict__ deg, const int* __restrict__ boff,
                        int* __restrict__ rp, int* __restrict__ cur, float* __restrict__ invd) {
    __shared__ int s[256];
    int t = threadIdx.x;
    int i = blockIdx.x * 256 + t;
    int v = (i < NN) ? deg[i] : 0;
    s[t] = v; __syncthreads();
    for (int o = 1; o < 256; o <<= 1) {
        int u = (t >= o) ? s[t - o] : 0;
        __syncthreads(); s[t] += u; __syncthreads();
    }
    int ex = s[t] - v + boff[blockIdx.x];
    if (i < NN) {
        rp[i] = ex; cur[i] = ex;
        invd[i] = 1.f / (float)(v > 0 ? v : 1);
    }
    if (i == NN - 1) rp[NN] = NE;
}

// spline basis per edge, scattered into dst-sorted order.
// pseudo in [0,1) -> i0,i1 in 0..3 -> corners are k00+{0,1,5,6}.
__global__ void k_scatter(const float* __restrict__ ea, const int* __restrict__ src,
                          const int* __restrict__ dst, int* __restrict__ cur,
                          float4* __restrict__ mB, int2* __restrict__ mI) {
    int e = blockIdx.x * 256 + threadIdx.x;
    if (e >= NE) return;
    float p0 = ea[e*3+0], p1 = ea[e*3+1];
    float v0 = p0*4.f, v1 = p1*4.f;
    float b0 = fminf(fmaxf(floorf(v0),0.f),4.f);
    float b1 = fminf(fmaxf(floorf(v1),0.f),4.f);
    float f0 = v0-b0, f1 = v1-b1;
    int i0 = (int)b0, i1 = (int)b1;
    float B00 = (1.f-f0)*(1.f-f1);
    float B01 = (1.f-f0)*f1;
    float B10 = f0*(1.f-f1);
    float B11 = f0*f1;
    int k00 = i0*5 + i1;
    int dn = dst[e];
    int pos = atomicAdd(&cur[dn], 1);
    mB[pos] = make_float4(B00,B01,B10,B11);
    mI[pos] = make_int2(k00, src[e]);
}

// pack+transpose weights to bf16 [outcol][KT]:
// T1: 64 rows. T23: 128 rows (W2 | W3). Tr: 16 rows (4 valid). TcTo: 128 rows (Wc 112 | Wo 16).
__global__ void k_prepw(const float* W1,const float* R1,const float* W2,const float* R2,
                        const float* W3,const float* R3,const float* Wr,const float* Rr,
                        const float* Wc,const float* Rc,const float* Wo,const float* Ro,
                        ushort* T1, ushort* T23, ushort* Tr, ushort* TcTo) {
    int b = blockIdx.x;
    const float* W; const float* R; ushort* T; int od; int col;
    if      (b < 64)  { W=W1; R=R1; T=T1  + (long)b*KT;       od=64;  col=b;     }
    else if (b < 128) { W=W2; R=R2; T=T23 + (long)(b-64)*KT;  od=64;  col=b-64;  }
    else if (b < 192) { W=W3; R=R3; T=T23 + (long)(b-64)*KT;  od=64;  col=b-128; }
    else if (b < 208) { W=Wr; R=Rr; T=Tr  + (long)(b-192)*KT; od=4;   col=b-192; }
    else if (b < 320) { W=Wc; R=Rc; T=TcTo+ (long)(b-208)*KT; od=101; col=b-208; }
    else              { W=Wo; R=Ro; T=TcTo+ (long)(b-208)*KT; od=1;   col=b-320; }
    for (int kc = threadIdx.x; kc < KT; kc += 256) {
        float v = 0.f;
        if (col < od) v = (kc < KD) ? W[(long)kc*od + col] : R[(long)(kc-KD)*od + col];
        T[kc] = f2bf(v);
    }
}

// ---------------- aggregation: one wave per node, phase-split for MLP ----------------
#define AGGC(K, A_, B_, C_, D_) case K: A_ += bb.x*xu; B_ += bb.y*xu; C_ += bb.z*xu; D_ += bb.w*xu; break;

template<bool NORM>
__global__ void k_agg(const int* __restrict__ rp, const float4* __restrict__ mB,
                      const int2* __restrict__ mI, const float* __restrict__ f,
                      const float* __restrict__ invd,
                      const float* __restrict__ st, const float* __restrict__ g,
                      const float* __restrict__ be, ushort* __restrict__ A) {
    int wid = (blockIdx.x * 256 + threadIdx.x) >> 6;
    wid = __builtin_amdgcn_readfirstlane(wid);   // wave-uniform -> scalar loads for rp/mI/mB
    int l = threadIdx.x & 63;
    if (wid >= NN) return;
    float na = 0.f, nc = 0.f;
    if (NORM) {
        const float inv_n = 1.f / (float)NN;
        float mm = st[l] * inv_n;
        float var = st[64 + l] * inv_n - mm * mm;
        float rs = rsqrtf(var + 1e-5f);
        na = g[l] * rs; nc = be[l] - mm * na;
    }
    float a00=0.f,a01=0.f,a02=0.f,a03=0.f,a04=0.f;
    float a05=0.f,a06=0.f,a07=0.f,a08=0.f,a09=0.f;
    float a10=0.f,a11=0.f,a12=0.f,a13=0.f,a14=0.f;
    float a15=0.f,a16=0.f,a17=0.f,a18=0.f,a19=0.f;
    float a20=0.f,a21=0.f,a22=0.f,a23=0.f,a24=0.f;
    int beg = rp[wid], end = rp[wid + 1];
    for (int e0 = beg; e0 < end; e0 += 8) {
        // phase 1: edge metadata (uniform -> SMEM path)
        int2 m[8];
        #pragma unroll
        for (int u = 0; u < 8; ++u) {
            int e = e0 + u;
            m[u] = mI[(e < end) ? e : beg];
        }
        // phase 2: issue ALL 8 gathers before any consumption
        float xv[8];
        #pragma unroll
        for (int u = 0; u < 8; ++u) xv[u] = f[(long)m[u].y * CIN + l];
        __builtin_amdgcn_sched_barrier(0);
        // phase 3: basis weights (uniform -> SMEM path), zero the tail
        float4 b[8];
        #pragma unroll
        for (int u = 0; u < 8; ++u) {
            int e = e0 + u;
            b[u] = mB[(e < end) ? e : beg];
            if (e >= end) b[u] = make_float4(0,0,0,0);
        }
        __builtin_amdgcn_sched_barrier(0);
        // phase 4: consume
        #pragma unroll
        for (int u = 0; u < 8; ++u) {
            float xu = xv[u];
            if (NORM) xu = fmaxf(xu * na + nc, 0.f);
            int k00 = __builtin_amdgcn_readfirstlane(m[u].x);
            float4 bb = b[u];
            switch (k00) {
                AGGC(0,  a00,a01,a05,a06)
                AGGC(1,  a01,a02,a06,a07)
                AGGC(2,  a02,a03,a07,a08)
                AGGC(3,  a03,a04,a08,a09)
                AGGC(5,  a05,a06,a10,a11)
                AGGC(6,  a06,a07,a11,a12)
                AGGC(7,  a07,a08,a12,a13)
                AGGC(8,  a08,a09,a13,a14)
                AGGC(10, a10,a11,a15,a16)
                AGGC(11, a11,a12,a16,a17)
                AGGC(12, a12,a13,a17,a18)
                AGGC(13, a13,a14,a18,a19)
                AGGC(15, a15,a16,a20,a21)
                AGGC(16, a16,a17,a21,a22)
                AGGC(17, a17,a18,a22,a23)
                AGGC(18, a18,a19,a23,a24)
                default: break;
            }
        }
    }
    float s = invd[wid];
    ushort* rb = A + (long)wid * KT + l;
    #define STO(K, V) rb[K*CIN] = f2bf((V) * s);
    STO(0,a00)  STO(1,a01)  STO(2,a02)  STO(3,a03)  STO(4,a04)
    STO(5,a05)  STO(6,a06)  STO(7,a07)  STO(8,a08)  STO(9,a09)
    STO(10,a10) STO(11,a11) STO(12,a12) STO(13,a13) STO(14,a14)
    STO(15,a15) STO(16,a16) STO(17,a17) STO(18,a18) STO(19,a19)
    STO(20,a20) STO(21,a21) STO(22,a22) STO(23,a23) STO(24,a24)
    #undef STO
    float rv = f[(long)wid * CIN + l];
    if (NORM) rv = fmaxf(rv * na + nc, 0.f);
    rb[KD] = f2bf(rv);
}

// ---------------- GEMM: A[30016 x 1664] bf16 x B[N x 1664] bf16 -> f32 ----------------
// BM=32 rows/block, 512 threads (8 waves), BK=128 (13 macro-steps), 938 blocks (~3.7/CU).
// A double-buffered in LDS (16 KB): XOR-swizzled ds_write + matching ds_read, conflict-free.
// B-fragments from global (L2-resident), 1 load per 2 MFMA.
// MODE 0: N=64  (T1)  -> y1 + st1, K-split [0,7)/[7,13), no bias
// MODE 1: N=128 (T23) -> waves 0-3: y2+st2, waves 4-7: y3+st3
// MODE 2: N=16  (Tr)  -> out stride 4 (4 valid cols), K round-robin over 8 waves, bias
// MODE 3: N=128 (TcTo)-> waves 0-6: cls (101 valid, stride 101, bias), wave 7: obj (1 col, bias)
template<int MODE>
__global__ void k_gemm(const ushort* __restrict__ A, const ushort* __restrict__ B,
                       float* __restrict__ o0, float* __restrict__ o1,
                       float* __restrict__ s0, float* __restrict__ s1,
                       const float* __restrict__ b0, const float* __restrict__ b1) {
    __shared__ ushort As[2 * 4096];           // 2 x 8 KB
    f32x4* part = (f32x4*)As;                 // epilogue overlay (As dead by then)
    const int tid = threadIdx.x, w = tid >> 6, l = tid & 63;
    const int m0 = blockIdx.x * BM;

    int colrow;
    if constexpr (MODE == 0)      colrow = ((w & 3) << 4) + (l & 15);
    else if constexpr (MODE == 2) colrow = (l & 15);
    else                          colrow = (w << 4) + (l & 15);
    const ushort* Bp = B + (long)colrow * KT + ((l >> 4) << 3);

    // staging map: thread t loads one int4; row = t>>4 (0..31), j = t&15
    const int r0 = tid >> 4, j0 = tid & 15;
    const ushort* Asrc = A + (long)(m0 + r0) * KT + (j0 << 3);
    const int swzo = ((j0 ^ (r0 & 7)) << 4);

    f32x4 acc[2];
    acc[0] = (f32x4){0.f,0.f,0.f,0.f};
    acc[1] = (f32x4){0.f,0.f,0.f,0.f};

    // prologue: stage macro-step 0 into buf 0
    *(int4*)((char*)As + r0 * 256 + swzo) = *(const int4*)(Asrc);
    __syncthreads();

    int buf = 0;
    for (int ks = 0; ks < KMAC; ++ks) {
        int4 vn;
        if (ks < KMAC - 1) vn = *(const int4*)(Asrc + (ks + 1) * 128);
        bool act;
        if constexpr (MODE == 0)      act = (w < 4) ? (ks < 7) : (ks >= 7);
        else if constexpr (MODE == 2) act = ((ks & 7) == w);
        else                          act = true;
        if (act) {
            const char* Ab = (const char*)As + buf * 8192;
            #pragma unroll
            for (int s = 0; s < 4; ++s) {
                bf16x8 bb = *(const bf16x8*)(Bp + ks * 128 + s * 32);
                #pragma unroll
                for (int m = 0; m < 2; ++m) {
                    int r = (m << 4) + (l & 15);
                    int j = (s << 2) + (l >> 4);
                    bf16x8 a = *(const bf16x8*)(Ab + r * 256 + ((j ^ (r & 7)) << 4));
                    acc[m] = __builtin_amdgcn_mfma_f32_16x16x32_bf16(a, bb, acc[m], 0, 0, 0);
                }
            }
        }
        if (ks < KMAC - 1)
            *(int4*)((char*)As + (buf ^ 1) * 8192 + r0 * 256 + swzo) = vn;
        __syncthreads();
        buf ^= 1;
    }

    // ---- epilogue (part[] overlays As; all As reads completed before final barrier) ----
    auto emit = [&](f32x4* ac, float* out, int ostride, int col, int odcap, float bv, float* stats) {
        float p1 = 0.f, p2 = 0.f;
        #pragma unroll
        for (int m = 0; m < 2; ++m) {
            #pragma unroll
            for (int r = 0; r < 4; ++r) {
                int row = m0 + (m << 4) + ((l >> 4) << 2) + r;
                if (row < NN) {
                    float v = ac[m][r] + bv;
                    if (col < odcap) out[(long)row * ostride + col] = v;
                    p1 += v; p2 += v * v;
                }
            }
        }
        if (stats) {
            p1 += __shfl_down(p1, 32); p2 += __shfl_down(p2, 32);
            p1 += __shfl_down(p1, 16); p2 += __shfl_down(p2, 16);
            if (l < 16) { atomicAdd(&stats[col], p1); atomicAdd(&stats[64 + col], p2); }
        }
    };

    if constexpr (MODE == 0) {
        if (w >= 4) {
            #pragma unroll
            for (int m = 0; m < 2; ++m) part[((w & 3) << 7) + (l << 1) + m] = acc[m];
        }
        __syncthreads();
        if (w < 4) {
            #pragma unroll
            for (int m = 0; m < 2; ++m) acc[m] += part[((w & 3) << 7) + (l << 1) + m];
            emit(acc, o0, 64, ((w & 3) << 4) + (l & 15), 64, 0.f, s0);
        }
    } else if constexpr (MODE == 1) {
        if (w < 4) emit(acc, o0, 64, (w << 4) + (l & 15), 64, 0.f, s0);
        else       emit(acc, o1, 64, ((w - 4) << 4) + (l & 15), 64, 0.f, s1);
    } else if constexpr (MODE == 2) {
        if (w > 0) {
            #pragma unroll
            for (int m = 0; m < 2; ++m) part[((w - 1) << 7) + (l << 1) + m] = acc[m];
        }
        __syncthreads();
        if (w == 0) {
            for (int i = 0; i < 7; ++i) {
                #pragma unroll
                for (int m = 0; m < 2; ++m) acc[m] += part[(i << 7) + (l << 1) + m];
            }
            int col = l & 15;
            emit(acc, o0, 4, col, 4, (col < 4) ? b0[col] : 0.f, nullptr);
        }
    } else {
        if (w < 7) {
            int col = (w << 4) + (l & 15);
            emit(acc, o0, 101, col, 101, (col < 101) ? b0[col] : 0.f, nullptr);
        } else {
            int col = l & 15;
            emit(acc, o1, 1, col, 1, b1[0], nullptr);
        }
    }
}

// ---------------- host launch ----------------
extern "C" void kernel_launch(void* const* d_in, const int* in_sizes, int n_in,
                              void* d_out, int out_size, void* d_ws, size_t ws_size,
                              hipStream_t stream) {
    const float* x    = (const float*)d_in[0];
    const float* ea   = (const float*)d_in[1];
    const int*   src  = (const int*)d_in[2];
    const int*   dst  = (const int*)d_in[3];
    const float* W1   = (const float*)d_in[4];
    const float* R1   = (const float*)d_in[5];
    const float* g1   = (const float*)d_in[6];
    const float* be1  = (const float*)d_in[7];
    const float* W2   = (const float*)d_in[8];
    const float* R2   = (const float*)d_in[9];
    const float* g2   = (const float*)d_in[10];
    const float* be2  = (const float*)d_in[11];
    const float* W3   = (const float*)d_in[12];
    const float* R3   = (const float*)d_in[13];
    const float* g3   = (const float*)d_in[14];
    const float* be3  = (const float*)d_in[15];
    const float* Wr   = (const float*)d_in[16];
    const float* Rr   = (const float*)d_in[17];
    const float* br   = (const float*)d_in[18];
    const float* Wc   = (const float*)d_in[19];
    const float* Rc   = (const float*)d_in[20];
    const float* bc   = (const float*)d_in[21];
    const float* Wo   = (const float*)d_in[22];
    const float* Ro   = (const float*)d_in[23];
    const float* bo   = (const float*)d_in[24];
    float* out = (float*)d_out;

    char* p = (char*)d_ws;
    auto alloc = [&](size_t bytes) { char* r = p; p += (bytes + 255) & ~(size_t)255; return r; };
    float4* mB   = (float4*)alloc((size_t)NE * 16);
    int2*   mI   = (int2*)  alloc((size_t)NE * 8);
    int*    deg  = (int*)   alloc((size_t)NN * 4);
    int*    rp   = (int*)   alloc((size_t)(NN + 1) * 4);
    int*    cur  = (int*)   alloc((size_t)NN * 4);
    float*  invd = (float*) alloc((size_t)NN * 4);
    int*    bsum = (int*)   alloc((size_t)NBS * 4);
    int*    boff = (int*)   alloc((size_t)NBS * 4);
    ushort* T1   = (ushort*)alloc((size_t)64  * KT * 2);
    ushort* T23  = (ushort*)alloc((size_t)128 * KT * 2);
    ushort* Tr   = (ushort*)alloc((size_t)16  * KT * 2);
    ushort* TcTo = (ushort*)alloc((size_t)128 * KT * 2);
    float*  y1   = (float*) alloc((size_t)NN * CIN * 4);
    float*  y2   = (float*) alloc((size_t)NN * CIN * 4);
    float*  y3   = (float*) alloc((size_t)NN * CIN * 4);
    float*  stats= (float*) alloc(3 * 128 * 4);
    ushort* A    = (ushort*)alloc((size_t)MROWS * KT * 2);   // ~99.9 MB
    float* st1 = stats, *st2 = stats + 128, *st3 = stats + 256;

    hipMemsetAsync(deg, 0, (size_t)NN * 4, stream);
    hipMemsetAsync(stats, 0, 3 * 128 * 4, stream);

    k_count  <<<1875, 256, 0, stream>>>(dst, deg);
    k_scan1  <<<NBS, 256, 0, stream>>>(deg, bsum);
    k_scan2  <<<1, 128, 0, stream>>>(bsum, boff);
    k_scan3  <<<NBS, 256, 0, stream>>>(deg, boff, rp, cur, invd);
    k_scatter<<<1875, 256, 0, stream>>>(ea, src, dst, cur, mB, mI);
    k_prepw  <<<336, 256, 0, stream>>>(W1,R1,W2,R2,W3,R3,Wr,Rr,Wc,Rc,Wo,Ro,T1,T23,Tr,TcTo);

    // conv1
    k_agg<false><<<7500, 256, 0, stream>>>(rp, mB, mI, x, invd, nullptr, nullptr, nullptr, A);
    k_gemm<0><<<NBLK, 512, 0, stream>>>(A, T1, y1, nullptr, st1, nullptr, nullptr, nullptr);
    // conv2 + conv3 (shared aggregation of BN1(y1))
    k_agg<true><<<7500, 256, 0, stream>>>(rp, mB, mI, y1, invd, st1, g1, be1, A);
    k_gemm<1><<<NBLK, 512, 0, stream>>>(A, T23, y2, y3, st2, st3, nullptr, nullptr);
    // regr head on BN2(y2)
    k_agg<true><<<7500, 256, 0, stream>>>(rp, mB, mI, y2, invd, st2, g2, be2, A);
    k_gemm<2><<<NBLK, 512, 0, stream>>>(A, Tr, out + REG_OFF, nullptr, nullptr, nullptr, br, nullptr);
    // cls + obj heads on BN3(y3)
    k_agg<true><<<7500, 256, 0, stream>>>(rp, mB, mI, y3, invd, st3, g3, be3, A);
    k_gemm<3><<<NBLK, 512, 0, stream>>>(A, TcTo, out, out + OBJ_OFF, nullptr, nullptr, bc, bo);
}